// Round 1
// 1476.316 us; speedup vs baseline: 1.0184x; 1.0184x over previous
//
#include <hip/hip_runtime.h>
#include <stdint.h>

// ---------------------------------------------------------------------------
// LocalDino forward on MI355X (gfx950).
// Inputs: float32. OUTPUT: float32 (reference dtype). Internal: bf16 + f32 acc.
// Heavy math via mfma_f32_16x16x32_bf16, 128x128 tile, BK=32,
// global_load_lds(16B) staging. Decoder convs = implicit-GEMM NHWC with a
// triple-buffered, counted-vmcnt software pipeline (conv blocks are
// latency-bound at 1 block/CU; transformer GEMMs keep the simple loop).
// Rich sequential workspace layout, NO chunking, peak 110,395,648 B.
// ---------------------------------------------------------------------------

typedef unsigned short u16;
typedef __bf16 bf16x8 __attribute__((ext_vector_type(8)));
typedef short  s16x8  __attribute__((ext_vector_type(8)));
typedef float  f32x4  __attribute__((ext_vector_type(4)));

__device__ __forceinline__ float b2f(u16 x) { return __uint_as_float(((unsigned)x) << 16); }
__device__ __forceinline__ u16 f2b(float f) {
  unsigned u = __float_as_uint(f);
  unsigned r = (u + 0x7fffu + ((u >> 16) & 1u)) >> 16;   // RNE
  return (u16)r;
}
__device__ __forceinline__ void async16(u16* lds, const u16* g) {
  __builtin_amdgcn_global_load_lds((const __attribute__((address_space(1))) void*)g,
                                   (__attribute__((address_space(3))) void*)lds, 16, 0, 0);
}
__device__ __forceinline__ float gelu_f(float x) {
  return 0.5f * x * (1.0f + erff(x * 0.70710678118654752f));  // exact gelu
}

// f32 -> bf16 canonicalization
__global__ __launch_bounds__(256) void cvt_f2b(const float* __restrict__ src,
                                               u16* __restrict__ dst, int n) {
  const int i = (blockIdx.x * 256 + threadIdx.x) * 4;
  if (i + 3 < n) {
    const float4 v = *(const float4*)(src + i);
    dst[i] = f2b(v.x); dst[i + 1] = f2b(v.y); dst[i + 2] = f2b(v.z); dst[i + 3] = f2b(v.w);
  }
}

// ---------------------------------------------------------------------------
// bf16 GEMM: C[m,n] = sum_k A[m,k]*B[n,k] (+bias[n]) (+gelu). Cb bf16 output.
// Batched via blockIdx.z: off = (z/ZH)*s?b + (z%ZH)*s?h.
// ---------------------------------------------------------------------------
__global__ __launch_bounds__(256) void gemm_bt(
    const u16* __restrict__ A, int lda, long long sAb, long long sAh,
    const u16* __restrict__ B, int ldb, long long sBb, long long sBh,
    u16* __restrict__ Cb, int ldc, long long sCb, long long sCh,
    const float* __restrict__ bias, int epi, int ZH, int nk)
{
  __shared__ u16 As[128 * 32];
  __shared__ u16 Bs[128 * 32];
  const int tid = threadIdx.x;
  const int zb = blockIdx.z / ZH, zh = blockIdx.z % ZH;
  const u16* Ab = A + zb * sAb + zh * sAh;
  const u16* Bb = B + zb * sBb + zh * sBh;
  const int m0 = blockIdx.y << 7, n0 = blockIdx.x << 7;
  const int wave = tid >> 6, lane = tid & 63;
  const int wm = (wave >> 1) << 6, wn = (wave & 1) << 6;
  const int lr = lane & 15, lq = lane >> 4;
  const int rowb = tid >> 2, kc = (tid & 3) << 3;

  f32x4 acc[4][4] = {};

  for (int kt = 0; kt < nk; ++kt) {
    const int k0 = kt << 5;
    __syncthreads();
    async16(&As[tid * 8],         Ab + (long long)(m0 + rowb)      * lda + (k0 + kc));
    async16(&As[(tid + 256) * 8], Ab + (long long)(m0 + rowb + 64) * lda + (k0 + kc));
    async16(&Bs[tid * 8],         Bb + (long long)(n0 + rowb)      * ldb + (k0 + kc));
    async16(&Bs[(tid + 256) * 8], Bb + (long long)(n0 + rowb + 64) * ldb + (k0 + kc));
    __syncthreads();

    bf16x8 af[4], bfv[4];
#pragma unroll
    for (int mi = 0; mi < 4; ++mi)
      af[mi] = __builtin_bit_cast(bf16x8, *(const s16x8*)&As[((wm + mi * 16 + lr) << 5) + (lq << 3)]);
#pragma unroll
    for (int ni = 0; ni < 4; ++ni)
      bfv[ni] = __builtin_bit_cast(bf16x8, *(const s16x8*)&Bs[((wn + ni * 16 + lr) << 5) + (lq << 3)]);
#pragma unroll
    for (int mi = 0; mi < 4; ++mi)
#pragma unroll
      for (int ni = 0; ni < 4; ++ni)
        acc[mi][ni] = __builtin_amdgcn_mfma_f32_16x16x32_bf16(af[mi], bfv[ni], acc[mi][ni], 0, 0, 0);
  }

  const long long Co = zb * sCb + zh * sCh;
#pragma unroll
  for (int ni = 0; ni < 4; ++ni) {
    const int col = n0 + wn + ni * 16 + lr;
    const float badd = bias ? bias[col] : 0.0f;
#pragma unroll
    for (int mi = 0; mi < 4; ++mi) {
      const int row0 = m0 + wm + mi * 16 + (lq << 2);
#pragma unroll
      for (int r = 0; r < 4; ++r) {
        float v = acc[mi][ni][r] + badd;
        if (epi == 1) v = gelu_f(v);
        Cb[Co + (long long)(row0 + r) * ldc + col] = f2b(v);
      }
    }
  }
}

// ---------------------------------------------------------------------------
// Implicit-GEMM conv3x3 SAME, NHWC bf16 in, fused BN(eval)+ReLU, bf16 out.
// K = 9*Cin as ((dy*3+dx)*Cin + ci). Wr: [Npad x K] bf16. OOB -> zero page.
// TRIPLE-BUFFERED software pipeline: stage tile t+2 while computing tile t.
// Raw s_barrier + counted s_waitcnt vmcnt(8) keeps 2 batches (4 loads/thread
// each) in flight across barriers -- __syncthreads would drain vmcnt(0) and
// expose full load latency every tile (the measured 185 us / 8% MfmaUtil
// regime on the 128-block conv1 launch). nk must be divisible by 3 (288/144/
// 72/36 all are).
// ---------------------------------------------------------------------------
__global__ __launch_bounds__(256) void conv_gemm(
    const u16* __restrict__ U, const u16* __restrict__ Wr,
    u16* __restrict__ Out,
    const float* __restrict__ bn_g, const float* __restrict__ bn_b,
    const float* __restrict__ bn_m, const float* __restrict__ bn_v,
    const float* __restrict__ cb,
    const u16* __restrict__ zpg,
    int H, int W, int l2w, int l2hw, int l2c, int CoutReal, int Kdim, int nk)
{
  __shared__ u16 As[3][128 * 32];
  __shared__ u16 Bs[3][128 * 32];
  const int tid = threadIdx.x;
  const int m0 = blockIdx.y << 7, n0 = blockIdx.x << 7;
  const int wave = tid >> 6, lane = tid & 63;
  const int wm = (wave >> 1) << 6, wn = (wave & 1) << 6;
  const int lr = lane & 15, lq = lane >> 4;
  const int rowb = tid >> 2, kc = (tid & 3) << 3;
  const int hwmask = (1 << l2hw) - 1, wmask = (1 << l2w) - 1, cmask = (1 << l2c) - 1;

  f32x4 acc[4][4] = {};

  // Stage k-tile kt into buffer b: exactly 4 async16 per thread (2 A + 2 B).
  auto stage = [&](int kt, int b) {
    const int k0 = kt << 5;
#pragma unroll
    for (int i = 0; i < 2; ++i) {
      const int mrow = m0 + rowb + (i << 6);
      const int img = mrow >> l2hw;
      const int rem = mrow & hwmask;
      const int y = rem >> l2w, x = rem & wmask;
      const int k = k0 + kc;
      const int t = k >> l2c, ci = k & cmask;
      const int dy = (t * 86) >> 8;   // t/3 for t in [0,8]
      const int dx = t - dy * 3;
      const int yy = y + dy - 1, xx = x + dx - 1;
      const u16* src = ((unsigned)yy < (unsigned)H && (unsigned)xx < (unsigned)W)
          ? U + ((((long long)(img << l2hw) + (yy << l2w) + xx) << l2c) + ci)
          : zpg;
      async16(&As[b][(tid + (i << 8)) * 8], src);
      async16(&Bs[b][(tid + (i << 8)) * 8], Wr + (long long)(n0 + rowb + (i << 6)) * Kdim + (k0 + kc));
    }
  };

  // Prologue: tiles 0 and 1 in flight (8 loads/thread outstanding).
  stage(0, 0);
  stage(1, 1);

  for (int t0 = 0; t0 < nk; t0 += 3) {
#pragma unroll
    for (int p = 0; p < 3; ++p) {
      const int tt = t0 + p;
      // Issue tile tt+2 into buffer (p+2)%3 -- that buffer was last READ at
      // tile tt-1, and the trailing s_barrier of phase tt-1 ordered those
      // ds_reads before this overwrite.
      if (tt + 2 < nk) {
        stage(tt + 2, (p + 2) % 3);
        // 12 loads in flight (batches tt, tt+1, tt+2); wait until <=8 so the
        // oldest batch (tile tt, issued 2 phases ago) has landed in LDS.
        asm volatile("s_waitcnt vmcnt(8)" ::: "memory");
      } else if (tt + 1 < nk) {
        asm volatile("s_waitcnt vmcnt(4)" ::: "memory");
      } else {
        asm volatile("s_waitcnt vmcnt(0)" ::: "memory");
      }
      // Publish: every wave has drained its own batch-tt loads -> after this
      // barrier all of tile tt's LDS data is visible to all waves.
      asm volatile("s_barrier" ::: "memory");

      bf16x8 af[4], bfv[4];
#pragma unroll
      for (int mi = 0; mi < 4; ++mi)
        af[mi] = __builtin_bit_cast(bf16x8, *(const s16x8*)&As[p][((wm + mi * 16 + lr) << 5) + (lq << 3)]);
#pragma unroll
      for (int ni = 0; ni < 4; ++ni)
        bfv[ni] = __builtin_bit_cast(bf16x8, *(const s16x8*)&Bs[p][((wn + ni * 16 + lr) << 5) + (lq << 3)]);
#pragma unroll
      for (int mi = 0; mi < 4; ++mi)
#pragma unroll
        for (int ni = 0; ni < 4; ++ni)
          acc[mi][ni] = __builtin_amdgcn_mfma_f32_16x16x32_bf16(af[mi], bfv[ni], acc[mi][ni], 0, 0, 0);

      // Protect buffer p from next phase's overwrite; ds_reads are already
      // retired (compiler lgkmcnt waits precede the MFMAs that consume them),
      // and the in-flight global_load_lds batches stay in flight across it.
      asm volatile("s_barrier" ::: "memory");
    }
  }

#pragma unroll
  for (int ni = 0; ni < 4; ++ni) {
    const int col = n0 + wn + ni * 16 + lr;
    const bool ok = col < CoutReal;
    float bs = 0.0f, bsh = 0.0f;
    if (ok) {
      const float inv = rsqrtf(bn_v[col] + 1e-5f);
      bs = bn_g[col] * inv;
      bsh = (cb[col] - bn_m[col]) * bs + bn_b[col];
    }
#pragma unroll
    for (int mi = 0; mi < 4; ++mi) {
      const int row0 = m0 + wm + mi * 16 + (lq << 2);
#pragma unroll
      for (int r = 0; r < 4; ++r) {
        if (ok) {
          const float v = fmaxf(acc[mi][ni][r] * bs + bsh, 0.0f);
          Out[(long long)(row0 + r) * CoutReal + col] = f2b(v);
        }
      }
    }
  }
}

// --------------------------- auxiliary kernels -----------------------------

// patches f32 [64][3][128][128] -> A_pe bf16 [4096 tok][768] (k=c*256+ky*16+kx)
__global__ void pe_gather(const float* __restrict__ patches, u16* __restrict__ Ape) {
  const int t = blockIdx.x, tid = threadIdx.x;
  const int img = t >> 6, pos = t & 63, ty = pos >> 3, tx = pos & 7;
  const float* base = patches + (long long)img * 3 * 128 * 128;
  u16* dst = Ape + (long long)t * 768;
  for (int k = tid; k < 768; k += 256) {
    const int c = k >> 8, rr = k & 255, ky = rr >> 4, kx = rr & 15;
    dst[k] = f2b(base[c * 16384 + (ty * 16 + ky) * 128 + tx * 16 + kx]);
  }
}

// V slice of qkv -> Vt [z=bq*8+h][128 d][512 t] bf16 (LDS transpose)
__global__ void vt_transpose(const u16* __restrict__ qkv, u16* __restrict__ Vt) {
  __shared__ u16 lds[64 * 130];
  const int tt = blockIdx.x;       // t-tile 0..7
  const int z = blockIdx.y;        // 0..63
  const int bq = z >> 3, h = z & 7;
  const int tid = threadIdx.x;
  for (int idx = tid; idx < 64 * 128; idx += 256) {
    const int t = idx >> 7, d = idx & 127;
    lds[t * 130 + d] = qkv[(long long)(bq * 512 + tt * 64 + t) * 3072 + 2048 + h * 128 + d];
  }
  __syncthreads();
  for (int idx = tid; idx < 64 * 128; idx += 256) {
    const int d = idx >> 6, t = idx & 63;
    Vt[(long long)z * 65536 + d * 512 + tt * 64 + t] = lds[t * 130 + d];
  }
}

// in-place row softmax with 1/sqrt(128) scale on bf16 rows of 512
__global__ __launch_bounds__(256) void softmax_rows(u16* __restrict__ P) {
  __shared__ float red[8];
  const long long base = (long long)blockIdx.x * 512;
  const int tid = threadIdx.x;
  const float sc = 0.08838834764831845f;
  float x0 = b2f(P[base + tid]) * sc;
  float x1 = b2f(P[base + tid + 256]) * sc;
  float mx = fmaxf(x0, x1);
  for (int o = 32; o; o >>= 1) mx = fmaxf(mx, __shfl_down(mx, o));
  if ((tid & 63) == 0) red[tid >> 6] = mx;
  __syncthreads();
  mx = fmaxf(fmaxf(red[0], red[1]), fmaxf(red[2], red[3]));
  const float e0 = expf(x0 - mx), e1 = expf(x1 - mx);
  float s = e0 + e1;
  for (int o = 32; o; o >>= 1) s += __shfl_down(s, o);
  __syncthreads();
  if ((tid & 63) == 0) red[tid >> 6] = s;
  __syncthreads();
  s = red[0] + red[1] + red[2] + red[3];
  const float inv = 1.0f / s;
  P[base + tid] = f2b(e0 * inv);
  P[base + tid + 256] = f2b(e1 * inv);
}

// hs_b = LN(hs_b + P; g,b).  P bf16.  One block per row of 1024.
__global__ __launch_bounds__(256) void ln_kernel(
    u16* __restrict__ hsb, const u16* __restrict__ P,
    const float* __restrict__ gw, const float* __restrict__ bw)
{
  __shared__ float red[8];
  const int r = blockIdx.x, tid = threadIdx.x;
  float x[4], s = 0.0f, s2 = 0.0f;
#pragma unroll
  for (int i = 0; i < 4; ++i) {
    const int c = tid + i * 256;
    const float v = b2f(hsb[(long long)r * 1024 + c]) + b2f(P[(long long)r * 1024 + c]);
    x[i] = v; s += v; s2 += v * v;
  }
  for (int o = 32; o; o >>= 1) { s += __shfl_down(s, o); s2 += __shfl_down(s2, o); }
  if ((tid & 63) == 0) { red[tid >> 6] = s; red[4 + (tid >> 6)] = s2; }
  __syncthreads();
  s  = red[0] + red[1] + red[2] + red[3];
  s2 = red[4] + red[5] + red[6] + red[7];
  const float mean = s * (1.0f / 1024.0f);
  const float var = s2 * (1.0f / 1024.0f) - mean * mean;
  const float inv = rsqrtf(var + 1e-5f);
#pragma unroll
  for (int i = 0; i < 4; ++i) {
    const int c = tid + i * 256;
    const float y = (x[i] - mean) * inv * gw[c] + bw[c];
    hsb[(long long)r * 1024 + c] = f2b(y);
  }
}

// repack conv weights f32 [Cout][Cin][3][3] -> bf16 [Npad][9*Cin]
__global__ void repack_w(const float* __restrict__ src, u16* __restrict__ dst, int Cout, int l2c) {
  const int co = blockIdx.x, tid = threadIdx.x;
  const int Cin = 1 << l2c, K9 = 9 << l2c;
  for (int j = tid; j < K9; j += 256) {
    const int t = j >> l2c, ci = j & (Cin - 1);
    u16 v = 0;
    if (co < Cout) v = f2b(src[(long long)(co * Cin + ci) * 9 + t]);
    dst[(long long)co * K9 + j] = v;
  }
}

// bilinear x2 (half-pixel), bf16 NHWC -> bf16 NHWC (2H x 2W)
__global__ void ups2x(const u16* __restrict__ in, u16* __restrict__ out,
                      int l2h, int l2w, int l2c, long long total)
{
  const long long idx = (long long)blockIdx.x * 256 + threadIdx.x;
  if (idx >= total) return;
  const int H = 1 << l2h, W = 1 << l2w, C = 1 << l2c;
  const int c = (int)(idx & (C - 1));
  long long t = idx >> l2c;
  const int ox = (int)(t & (2 * W - 1)); t >>= (l2w + 1);
  const int oy = (int)(t & (2 * H - 1)); t >>= (l2h + 1);
  const int img = (int)t;
  const int iy = oy >> 1, ix = ox >> 1;
  int y0, y1, x0, x1; float wy0, wy1, wx0, wx1;
  if (oy & 1) { y0 = iy; y1 = min(iy + 1, H - 1); wy0 = 0.75f; wy1 = 0.25f; }
  else        { y0 = max(iy - 1, 0); y1 = iy;     wy0 = 0.25f; wy1 = 0.75f; }
  if (ox & 1) { x0 = ix; x1 = min(ix + 1, W - 1); wx0 = 0.75f; wx1 = 0.25f; }
  else        { x0 = max(ix - 1, 0); x1 = ix;     wx0 = 0.25f; wx1 = 0.75f; }
  const u16* base = in + (((long long)img) << (l2h + l2w + l2c));
  const float v00 = b2f(base[((((long long)y0 << l2w) + x0) << l2c) + c]);
  const float v01 = b2f(base[((((long long)y0 << l2w) + x1) << l2c) + c]);
  const float v10 = b2f(base[((((long long)y1 << l2w) + x0) << l2c) + c]);
  const float v11 = b2f(base[((((long long)y1 << l2w) + x1) << l2c) + c]);
  out[idx] = f2b(wy0 * (wx0 * v00 + wx1 * v01) + wy1 * (wx0 * v10 + wx1 * v11));
}

// 1x1 conv over 64 channels: C4 bf16 [262144][64] -> Z f32 [262144]
__global__ __launch_bounds__(256) void conv1x1_final(
    const u16* __restrict__ C4, const float* __restrict__ w5,
    const float* __restrict__ b5, float* __restrict__ Z)
{
  const int tid = threadIdx.x;
  const int px = blockIdx.x * 4 + (tid >> 6);
  const int lane = tid & 63;
  float v = b2f(C4[(long long)px * 64 + lane]) * w5[lane];
  for (int o = 32; o; o >>= 1) v += __shfl_down(v, o);
  if (lane == 0) Z[px] = v + b5[0];
}

// bilinear x2: Z f32 [64][64][64] -> out FLOAT32 [64][128][128]
__global__ void ups_final(const float* __restrict__ Z, float* __restrict__ out) {
  const int idx = blockIdx.x * 256 + threadIdx.x;
  const int ox = idx & 127, oy = (idx >> 7) & 127, img = idx >> 14;
  const int iy = oy >> 1, ix = ox >> 1;
  int y0, y1, x0, x1; float wy0, wy1, wx0, wx1;
  if (oy & 1) { y0 = iy; y1 = min(iy + 1, 63); wy0 = 0.75f; wy1 = 0.25f; }
  else        { y0 = max(iy - 1, 0); y1 = iy;  wy0 = 0.25f; wy1 = 0.75f; }
  if (ox & 1) { x0 = ix; x1 = min(ix + 1, 63); wx0 = 0.75f; wx1 = 0.25f; }
  else        { x0 = max(ix - 1, 0); x1 = ix;  wx0 = 0.25f; wx1 = 0.75f; }
  const float* zi = Z + (long long)img * 4096;
  const float v = wy0 * (wx0 * zi[y0 * 64 + x0] + wx1 * zi[y0 * 64 + x1]) +
                  wy1 * (wx0 * zi[y1 * 64 + x0] + wx1 * zi[y1 * 64 + x1]);
  out[idx] = v;
}

// ---------------------------------------------------------------------------
extern "C" void kernel_launch(void* const* d_in, const int* in_sizes, int n_in,
                              void* d_out, int out_size, void* d_ws, size_t ws_size,
                              hipStream_t stream)
{
  (void)in_sizes; (void)n_in; (void)out_size;
  if (ws_size < 110395648u) return;   // diagnostic: zero output => ws too small
  const float* patches = (const float*)d_in[0];
  const float* pe_w = (const float*)d_in[1];
  const float* pe_b = (const float*)d_in[2];
  const float* qkv_w = (const float*)d_in[3];
  const float* qkv_b = (const float*)d_in[4];
  const float* out_w = (const float*)d_in[5];
  const float* out_b = (const float*)d_in[6];
  const float* ln1_g = (const float*)d_in[7];
  const float* ln1_b = (const float*)d_in[8];
  const float* ff1_w = (const float*)d_in[9];
  const float* ff1_b = (const float*)d_in[10];
  const float* ff2_w = (const float*)d_in[11];
  const float* ff2_b = (const float*)d_in[12];
  const float* ln2_g = (const float*)d_in[13];
  const float* ln2_b = (const float*)d_in[14];
  const float* dwv[4] = {(const float*)d_in[15], (const float*)d_in[21], (const float*)d_in[27], (const float*)d_in[33]};
  const float* dbv[4] = {(const float*)d_in[16], (const float*)d_in[22], (const float*)d_in[28], (const float*)d_in[34]};
  const float* gv[4]  = {(const float*)d_in[17], (const float*)d_in[23], (const float*)d_in[29], (const float*)d_in[35]};
  const float* bev[4] = {(const float*)d_in[18], (const float*)d_in[24], (const float*)d_in[30], (const float*)d_in[36]};
  const float* mv[4]  = {(const float*)d_in[19], (const float*)d_in[25], (const float*)d_in[31], (const float*)d_in[37]};
  const float* vv[4]  = {(const float*)d_in[20], (const float*)d_in[26], (const float*)d_in[32], (const float*)d_in[38]};
  const float* dw5 = (const float*)d_in[39];
  const float* db5 = (const float*)d_in[40];
  float* outp = (float*)d_out;     // reference output dtype = float32
  char* ws = (char*)d_ws;

  // ---- workspace layout: rich sequential, peak 110,395,648 B --------------
  // transformer phase
  u16* HS_B = (u16*)(ws + 0);              // [4096][1024]
  u16* APE  = (u16*)(ws + 8388608);        // [4096][768] (dead before QKV)
  u16* QKV  = (u16*)(ws + 8388608);        // [4096][3072]   ends 33,554,432
  u16* VT   = (u16*)(ws + 33554432);       // [64][128][512] ends 41,943,040
  u16* SF   = (u16*)(ws + 41943040);       // [64][512][512] ends 75,497,472
  u16* FF1G = (u16*)(ws + 41943040);       // [4096][4096] (over dead SF)
  u16* ATT  = (u16*)(ws + 75497472);       // [4096][1024]   ends 83,886,080
  u16* P_B  = (u16*)(ws + 83886080);       // [4096][1024]   ends 92,274,688
  u16* W1   = (u16*)(ws + 92274688);       // 8.39M slot     ends 100,663,296
  u16* W2   = (u16*)(ws + 100663296);      // 8.39M slot     ends 109,051,904
  // decoder phase (all transformer buffers except HS_B dead)
  u16* WR1 = (u16*)(ws + 8388608);         // [512][9216]    ends 17,825,792
  u16* WR2 = (u16*)(ws + 17825792);        // [256][4608]    ends 20,185,088
  u16* WR3 = (u16*)(ws + 20185088);        // [128][2304]    ends 20,774,912
  u16* C1  = (u16*)(ws + 20774912);        // [4096][512]    ends 24,969,216
  u16* U1  = (u16*)(ws + 24969216);        // [64][16][16][512] ends 41,746,432
  u16* C2  = (u16*)(ws + 41746432);        // [16384][256]   ends 50,135,040
  u16* U2  = (u16*)(ws + 50135040);        // [64][32][32][256] ends 83,689,472
  u16* C3  = (u16*)(ws + 83689472);        // [65536][128]   ends 100,466,688
  u16* U3  = (u16*)(ws + 8388608);         // [64][64][64][128] ends 75,497,472 (over dead WR1-3/C1/U1/C2/U2)
  u16* C4  = (u16*)(ws + 75497472);        // [262144][64]   ends 109,051,904 (over dead C3/W-slots)
  u16* ZPG = (u16*)(ws + 109051904);       // 256 B zero page (live through all convs)
  u16* WR4 = (u16*)(ws + 109052160);       // [128][1152]    ends 109,347,072
  float* Z = (float*)(ws + 109347072);     // [262144] f32   ends 110,395,648

  // ---- patch embedding ----------------------------------------------------
  pe_gather<<<4096, 256, 0, stream>>>(patches, APE);
  cvt_f2b<<<768, 256, 0, stream>>>(pe_w, W1, 786432);
  gemm_bt<<<dim3(8, 32, 1), 256, 0, stream>>>(
      APE, 768, 0, 0, W1, 768, 0, 0,
      HS_B, 1024, 0, 0, pe_b, 0, 1, 24);

  // ---- transformer --------------------------------------------------------
  for (int l = 0; l < 2; ++l) {
    cvt_f2b<<<3072, 256, 0, stream>>>(qkv_w + (long long)l * 3145728, W1, 3145728);
    gemm_bt<<<dim3(24, 32, 1), 256, 0, stream>>>(
        HS_B, 1024, 0, 0, W1, 1024, 0, 0,
        QKV, 3072, 0, 0, qkv_b + l * 3072, 0, 1, 32);
    vt_transpose<<<dim3(8, 64), 256, 0, stream>>>(QKV, VT);
    // S = Q K^T for all 64 (batch,head)
    gemm_bt<<<dim3(4, 4, 64), 256, 0, stream>>>(
        QKV, 3072, 1572864, 128, QKV + 1024, 3072, 1572864, 128,
        SF, 512, 2097152, 262144, nullptr, 0, 8, 4);
    softmax_rows<<<32768, 256, 0, stream>>>(SF);
    // O = P V
    gemm_bt<<<dim3(1, 4, 64), 256, 0, stream>>>(
        SF, 512, 2097152, 262144, VT, 512, 524288, 65536,
        ATT, 1024, 524288, 128, nullptr, 0, 8, 16);
    cvt_f2b<<<1024, 256, 0, stream>>>(out_w + (long long)l * 1048576, W2, 1048576);
    gemm_bt<<<dim3(8, 32, 1), 256, 0, stream>>>(
        ATT, 1024, 0, 0, W2, 1024, 0, 0,
        P_B, 1024, 0, 0, out_b + l * 1024, 0, 1, 32);
    ln_kernel<<<4096, 256, 0, stream>>>(HS_B, P_B, ln1_g + l * 1024, ln1_b + l * 1024);
    cvt_f2b<<<4096, 256, 0, stream>>>(ff1_w + (long long)l * 4194304, W1, 4194304);
    cvt_f2b<<<4096, 256, 0, stream>>>(ff2_w + (long long)l * 4194304, W2, 4194304);
    gemm_bt<<<dim3(32, 32, 1), 256, 0, stream>>>(
        HS_B, 1024, 0, 0, W1, 1024, 0, 0,
        FF1G, 4096, 0, 0, ff1_b + l * 4096, 1, 1, 32);
    gemm_bt<<<dim3(8, 32, 1), 256, 0, stream>>>(
        FF1G, 4096, 0, 0, W2, 4096, 0, 0,
        P_B, 1024, 0, 0, ff2_b + l * 1024, 0, 1, 128);
    ln_kernel<<<4096, 256, 0, stream>>>(HS_B, P_B, ln2_g + l * 1024, ln2_b + l * 1024);
  }

  // ---- CNN decoder --------------------------------------------------------
  hipMemsetAsync((void*)ZPG, 0, 256, stream);
  repack_w<<<512, 256, 0, stream>>>(dwv[0], WR1, 512, 10);
  repack_w<<<256, 256, 0, stream>>>(dwv[1], WR2, 256, 9);
  repack_w<<<128, 256, 0, stream>>>(dwv[2], WR3, 128, 8);
  repack_w<<<128, 256, 0, stream>>>(dwv[3], WR4, 64, 7);

  conv_gemm<<<dim3(4, 32, 1), 256, 0, stream>>>(
      HS_B, WR1, C1, gv[0], bev[0], mv[0], vv[0], dbv[0], ZPG,
      8, 8, 3, 6, 10, 512, 9216, 288);
  ups2x<<<32768, 256, 0, stream>>>(C1, U1, 3, 3, 9, 8388608LL);
  conv_gemm<<<dim3(2, 128, 1), 256, 0, stream>>>(
      U1, WR2, C2, gv[1], bev[1], mv[1], vv[1], dbv[1], ZPG,
      16, 16, 4, 8, 9, 256, 4608, 144);
  ups2x<<<65536, 256, 0, stream>>>(C2, U2, 4, 4, 8, 16777216LL);
  conv_gemm<<<dim3(1, 512, 1), 256, 0, stream>>>(
      U2, WR3, C3, gv[2], bev[2], mv[2], vv[2], dbv[2], ZPG,
      32, 32, 5, 10, 8, 128, 2304, 72);
  ups2x<<<131072, 256, 0, stream>>>(C3, U3, 5, 5, 7, 33554432LL);
  conv_gemm<<<dim3(1, 2048, 1), 256, 0, stream>>>(
      U3, WR4, C4, gv[3], bev[3], mv[3], vv[3], dbv[3], ZPG,
      64, 64, 6, 12, 7, 64, 1152, 36);
  conv1x1_final<<<65536, 256, 0, stream>>>(C4, dw5, db5, Z);
  ups_final<<<4096, 256, 0, stream>>>(Z, outp);
}

// Round 2
// 1458.103 us; speedup vs baseline: 1.0311x; 1.0125x over previous
//
#include <hip/hip_runtime.h>
#include <stdint.h>

// ---------------------------------------------------------------------------
// LocalDino forward on MI355X (gfx950).
// Inputs: float32. OUTPUT: float32 (reference dtype). Internal: bf16 + f32 acc.
// Heavy math via mfma_f32_16x16x32_bf16. Transformer GEMMs: 128x128 tile,
// BK=32, global_load_lds(16B) staging (m97 structure). Decoder convs:
// implicit-GEMM NHWC, 128x64 tile (2x block count -> all 256 CUs), BK=32,
// triple-buffered counted-vmcnt pipeline, and a conflict-free XOR-swizzled
// LDS layout (linear global_load_lds dest + permuted GLOBAL source + matching
// permuted read; R1 counters showed exactly 4 conflict-cycles per ds_read).
// Rich sequential workspace layout, NO chunking, peak 110,395,648 B.
// ---------------------------------------------------------------------------

typedef unsigned short u16;
typedef __bf16 bf16x8 __attribute__((ext_vector_type(8)));
typedef short  s16x8  __attribute__((ext_vector_type(8)));
typedef float  f32x4  __attribute__((ext_vector_type(4)));

__device__ __forceinline__ float b2f(u16 x) { return __uint_as_float(((unsigned)x) << 16); }
__device__ __forceinline__ u16 f2b(float f) {
  unsigned u = __float_as_uint(f);
  unsigned r = (u + 0x7fffu + ((u >> 16) & 1u)) >> 16;   // RNE
  return (u16)r;
}
__device__ __forceinline__ void async16(u16* lds, const u16* g) {
  __builtin_amdgcn_global_load_lds((const __attribute__((address_space(1))) void*)g,
                                   (__attribute__((address_space(3))) void*)lds, 16, 0, 0);
}
__device__ __forceinline__ float gelu_f(float x) {
  return 0.5f * x * (1.0f + erff(x * 0.70710678118654752f));  // exact gelu
}

// f32 -> bf16 canonicalization
__global__ __launch_bounds__(256) void cvt_f2b(const float* __restrict__ src,
                                               u16* __restrict__ dst, int n) {
  const int i = (blockIdx.x * 256 + threadIdx.x) * 4;
  if (i + 3 < n) {
    const float4 v = *(const float4*)(src + i);
    dst[i] = f2b(v.x); dst[i + 1] = f2b(v.y); dst[i + 2] = f2b(v.z); dst[i + 3] = f2b(v.w);
  }
}

// ---------------------------------------------------------------------------
// bf16 GEMM: C[m,n] = sum_k A[m,k]*B[n,k] (+bias[n]) (+gelu). Cb bf16 output.
// Batched via blockIdx.z: off = (z/ZH)*s?b + (z%ZH)*s?h.
// ---------------------------------------------------------------------------
__global__ __launch_bounds__(256) void gemm_bt(
    const u16* __restrict__ A, int lda, long long sAb, long long sAh,
    const u16* __restrict__ B, int ldb, long long sBb, long long sBh,
    u16* __restrict__ Cb, int ldc, long long sCb, long long sCh,
    const float* __restrict__ bias, int epi, int ZH, int nk)
{
  __shared__ u16 As[128 * 32];
  __shared__ u16 Bs[128 * 32];
  const int tid = threadIdx.x;
  const int zb = blockIdx.z / ZH, zh = blockIdx.z % ZH;
  const u16* Ab = A + zb * sAb + zh * sAh;
  const u16* Bb = B + zb * sBb + zh * sBh;
  const int m0 = blockIdx.y << 7, n0 = blockIdx.x << 7;
  const int wave = tid >> 6, lane = tid & 63;
  const int wm = (wave >> 1) << 6, wn = (wave & 1) << 6;
  const int lr = lane & 15, lq = lane >> 4;
  const int rowb = tid >> 2, kc = (tid & 3) << 3;

  f32x4 acc[4][4] = {};

  for (int kt = 0; kt < nk; ++kt) {
    const int k0 = kt << 5;
    __syncthreads();
    async16(&As[tid * 8],         Ab + (long long)(m0 + rowb)      * lda + (k0 + kc));
    async16(&As[(tid + 256) * 8], Ab + (long long)(m0 + rowb + 64) * lda + (k0 + kc));
    async16(&Bs[tid * 8],         Bb + (long long)(n0 + rowb)      * ldb + (k0 + kc));
    async16(&Bs[(tid + 256) * 8], Bb + (long long)(n0 + rowb + 64) * ldb + (k0 + kc));
    __syncthreads();

    bf16x8 af[4], bfv[4];
#pragma unroll
    for (int mi = 0; mi < 4; ++mi)
      af[mi] = __builtin_bit_cast(bf16x8, *(const s16x8*)&As[((wm + mi * 16 + lr) << 5) + (lq << 3)]);
#pragma unroll
    for (int ni = 0; ni < 4; ++ni)
      bfv[ni] = __builtin_bit_cast(bf16x8, *(const s16x8*)&Bs[((wn + ni * 16 + lr) << 5) + (lq << 3)]);
#pragma unroll
    for (int mi = 0; mi < 4; ++mi)
#pragma unroll
      for (int ni = 0; ni < 4; ++ni)
        acc[mi][ni] = __builtin_amdgcn_mfma_f32_16x16x32_bf16(af[mi], bfv[ni], acc[mi][ni], 0, 0, 0);
  }

  const long long Co = zb * sCb + zh * sCh;
#pragma unroll
  for (int ni = 0; ni < 4; ++ni) {
    const int col = n0 + wn + ni * 16 + lr;
    const float badd = bias ? bias[col] : 0.0f;
#pragma unroll
    for (int mi = 0; mi < 4; ++mi) {
      const int row0 = m0 + wm + mi * 16 + (lq << 2);
#pragma unroll
      for (int r = 0; r < 4; ++r) {
        float v = acc[mi][ni][r] + badd;
        if (epi == 1) v = gelu_f(v);
        Cb[Co + (long long)(row0 + r) * ldc + col] = f2b(v);
      }
    }
  }
}

// ---------------------------------------------------------------------------
// Implicit-GEMM conv3x3 SAME, NHWC bf16 in, fused BN(eval)+ReLU, bf16 out.
// K = 9*Cin as ((dy*3+dx)*Cin + ci). Wr: [Npad x K] bf16. OOB -> zero page.
// Tile 128(M) x 64(N), 4 waves in 2x2 (each 64x32 = 4x2 fragments).
// TRIPLE-BUFFERED counted-vmcnt pipeline: stage tile t+2 while computing t
// (3 async16/thread/stage -> steady-state s_waitcnt vmcnt(6)).
// LDS XOR swizzle: k-chunk lq of row r stored at slot lq ^ ((r>>1)&3); the
// staging source k-offset permutes accordingly (one per-thread constant),
// the fragment read applies the same XOR -> every 8-lane octet covers all 8
// four-bank groups exactly once (conflict-free; R1 measured 4 cyc/read).
// nk must be divisible by 3 (288/144/72/36 all are).
// ---------------------------------------------------------------------------
__global__ __launch_bounds__(256) void conv_gemm(
    const u16* __restrict__ U, const u16* __restrict__ Wr,
    u16* __restrict__ Out,
    const float* __restrict__ bn_g, const float* __restrict__ bn_b,
    const float* __restrict__ bn_m, const float* __restrict__ bn_v,
    const float* __restrict__ cb,
    const u16* __restrict__ zpg,
    int H, int W, int l2w, int l2hw, int l2c, int CoutReal, int Kdim, int nk)
{
  __shared__ u16 As[3][128 * 32];   // 8 KB per buffer
  __shared__ u16 Bs[3][64 * 32];    // 4 KB per buffer
  const int tid = threadIdx.x;
  const int m0 = blockIdx.y << 7, n0 = blockIdx.x << 6;
  const int wave = tid >> 6, lane = tid & 63;
  const int wm = (wave >> 1) << 6, wn = (wave & 1) << 5;
  const int lr = lane & 15, lq = lane >> 4;
  const int rowb = tid >> 2;
  // swizzled k-chunk this thread stages (same for A rows rowb, rowb+64, and B
  // row rowb, since adding 64 to the row doesn't change (row>>1)&3):
  const int kc_e = (((tid & 3) ^ ((tid >> 3) & 3)) << 3);
  // swizzled LDS element offset for fragment reads (row>>1&3 == lr>>1&3):
  const int kslot = ((lq ^ ((lr >> 1) & 3)) << 3);
  const int hwmask = (1 << l2hw) - 1, wmask = (1 << l2w) - 1, cmask = (1 << l2c) - 1;

  // Per-thread A-row geometry (phase-invariant): two halves i=0,1.
  int yA[2], xA[2];
  long long baseA[2];
  {
#pragma unroll
    for (int i = 0; i < 2; ++i) {
      const int mrow = m0 + rowb + (i << 6);
      const int img = mrow >> l2hw;
      const int rem = mrow & hwmask;
      yA[i] = rem >> l2w; xA[i] = rem & wmask;
      baseA[i] = (long long)(img << l2hw);
    }
  }
  const u16* Bbase = Wr + (long long)(n0 + rowb) * Kdim + kc_e;

  f32x4 acc[4][2] = {};

  // Stage k-tile kt into buffer b: exactly 3 async16 per thread (2 A + 1 B).
  auto stage = [&](int kt, int b) {
    const int k0 = kt << 5;
    const int k = k0 + kc_e;
    const int t = k >> l2c, ci = k & cmask;
    const int dy = (t * 86) >> 8;   // t/3 for t in [0,8]
    const int dx = t - dy * 3;
#pragma unroll
    for (int i = 0; i < 2; ++i) {
      const int yy = yA[i] + dy - 1, xx = xA[i] + dx - 1;
      const u16* src = ((unsigned)yy < (unsigned)H && (unsigned)xx < (unsigned)W)
          ? U + (((baseA[i] + (yy << l2w) + xx) << l2c) + ci)
          : zpg;
      async16(&As[b][(tid + (i << 8)) * 8], src);
    }
    async16(&Bs[b][tid * 8], Bbase + k0);
  };

  // Prologue: tiles 0 and 1 in flight (6 loads/thread outstanding).
  stage(0, 0);
  stage(1, 1);

  for (int t0 = 0; t0 < nk; t0 += 3) {
#pragma unroll
    for (int p = 0; p < 3; ++p) {
      const int tt = t0 + p;
      // Issue tile tt+2 into buffer (p+2)%3 (last read at tile tt-1; the
      // trailing s_barrier of phase tt-1 ordered those ds_reads before this).
      if (tt + 2 < nk) {
        stage(tt + 2, (p + 2) % 3);
        // 9 loads in flight (tiles tt, tt+1, tt+2); wait to <=6 so the oldest
        // batch (tile tt, issued 2 phases ago) has landed in LDS.
        asm volatile("s_waitcnt vmcnt(6)" ::: "memory");
      } else if (tt + 1 < nk) {
        asm volatile("s_waitcnt vmcnt(3)" ::: "memory");
      } else {
        asm volatile("s_waitcnt vmcnt(0)" ::: "memory");
      }
      // Publish tile tt's LDS data to all waves.
      asm volatile("s_barrier" ::: "memory");

      bf16x8 af[4], bfv[2];
#pragma unroll
      for (int mi = 0; mi < 4; ++mi)
        af[mi] = __builtin_bit_cast(bf16x8, *(const s16x8*)&As[p][((wm + mi * 16 + lr) << 5) + kslot]);
#pragma unroll
      for (int ni = 0; ni < 2; ++ni)
        bfv[ni] = __builtin_bit_cast(bf16x8, *(const s16x8*)&Bs[p][((wn + ni * 16 + lr) << 5) + kslot]);
#pragma unroll
      for (int mi = 0; mi < 4; ++mi)
#pragma unroll
        for (int ni = 0; ni < 2; ++ni)
          acc[mi][ni] = __builtin_amdgcn_mfma_f32_16x16x32_bf16(af[mi], bfv[ni], acc[mi][ni], 0, 0, 0);

      // Protect buffer p from next phase's overwrite (ds_reads retired via
      // compiler lgkmcnt before the MFMAs; global_load_lds stay in flight).
      asm volatile("s_barrier" ::: "memory");
    }
  }

#pragma unroll
  for (int ni = 0; ni < 2; ++ni) {
    const int col = n0 + wn + ni * 16 + lr;
    const bool ok = col < CoutReal;
    float bs = 0.0f, bsh = 0.0f;
    if (ok) {
      const float inv = rsqrtf(bn_v[col] + 1e-5f);
      bs = bn_g[col] * inv;
      bsh = (cb[col] - bn_m[col]) * bs + bn_b[col];
    }
#pragma unroll
    for (int mi = 0; mi < 4; ++mi) {
      const int row0 = m0 + wm + mi * 16 + (lq << 2);
#pragma unroll
      for (int r = 0; r < 4; ++r) {
        if (ok) {
          const float v = fmaxf(acc[mi][ni][r] * bs + bsh, 0.0f);
          Out[(long long)(row0 + r) * CoutReal + col] = f2b(v);
        }
      }
    }
  }
}

// --------------------------- auxiliary kernels -----------------------------

// patches f32 [64][3][128][128] -> A_pe bf16 [4096 tok][768] (k=c*256+ky*16+kx)
__global__ void pe_gather(const float* __restrict__ patches, u16* __restrict__ Ape) {
  const int t = blockIdx.x, tid = threadIdx.x;
  const int img = t >> 6, pos = t & 63, ty = pos >> 3, tx = pos & 7;
  const float* base = patches + (long long)img * 3 * 128 * 128;
  u16* dst = Ape + (long long)t * 768;
  for (int k = tid; k < 768; k += 256) {
    const int c = k >> 8, rr = k & 255, ky = rr >> 4, kx = rr & 15;
    dst[k] = f2b(base[c * 16384 + (ty * 16 + ky) * 128 + tx * 16 + kx]);
  }
}

// V slice of qkv -> Vt [z=bq*8+h][128 d][512 t] bf16 (LDS transpose)
__global__ void vt_transpose(const u16* __restrict__ qkv, u16* __restrict__ Vt) {
  __shared__ u16 lds[64 * 130];
  const int tt = blockIdx.x;       // t-tile 0..7
  const int z = blockIdx.y;        // 0..63
  const int bq = z >> 3, h = z & 7;
  const int tid = threadIdx.x;
  for (int idx = tid; idx < 64 * 128; idx += 256) {
    const int t = idx >> 7, d = idx & 127;
    lds[t * 130 + d] = qkv[(long long)(bq * 512 + tt * 64 + t) * 3072 + 2048 + h * 128 + d];
  }
  __syncthreads();
  for (int idx = tid; idx < 64 * 128; idx += 256) {
    const int d = idx >> 6, t = idx & 63;
    Vt[(long long)z * 65536 + d * 512 + tt * 64 + t] = lds[t * 130 + d];
  }
}

// in-place row softmax with 1/sqrt(128) scale on bf16 rows of 512
__global__ __launch_bounds__(256) void softmax_rows(u16* __restrict__ P) {
  __shared__ float red[8];
  const long long base = (long long)blockIdx.x * 512;
  const int tid = threadIdx.x;
  const float sc = 0.08838834764831845f;
  float x0 = b2f(P[base + tid]) * sc;
  float x1 = b2f(P[base + tid + 256]) * sc;
  float mx = fmaxf(x0, x1);
  for (int o = 32; o; o >>= 1) mx = fmaxf(mx, __shfl_down(mx, o));
  if ((tid & 63) == 0) red[tid >> 6] = mx;
  __syncthreads();
  mx = fmaxf(fmaxf(red[0], red[1]), fmaxf(red[2], red[3]));
  const float e0 = expf(x0 - mx), e1 = expf(x1 - mx);
  float s = e0 + e1;
  for (int o = 32; o; o >>= 1) s += __shfl_down(s, o);
  __syncthreads();
  if ((tid & 63) == 0) red[tid >> 6] = s;
  __syncthreads();
  s = red[0] + red[1] + red[2] + red[3];
  const float inv = 1.0f / s;
  P[base + tid] = f2b(e0 * inv);
  P[base + tid + 256] = f2b(e1 * inv);
}

// hs_b = LN(hs_b + P; g,b).  P bf16.  One block per row of 1024.
__global__ __launch_bounds__(256) void ln_kernel(
    u16* __restrict__ hsb, const u16* __restrict__ P,
    const float* __restrict__ gw, const float* __restrict__ bw)
{
  __shared__ float red[8];
  const int r = blockIdx.x, tid = threadIdx.x;
  float x[4], s = 0.0f, s2 = 0.0f;
#pragma unroll
  for (int i = 0; i < 4; ++i) {
    const int c = tid + i * 256;
    const float v = b2f(hsb[(long long)r * 1024 + c]) + b2f(P[(long long)r * 1024 + c]);
    x[i] = v; s += v; s2 += v * v;
  }
  for (int o = 32; o; o >>= 1) { s += __shfl_down(s, o); s2 += __shfl_down(s2, o); }
  if ((tid & 63) == 0) { red[tid >> 6] = s; red[4 + (tid >> 6)] = s2; }
  __syncthreads();
  s  = red[0] + red[1] + red[2] + red[3];
  s2 = red[4] + red[5] + red[6] + red[7];
  const float mean = s * (1.0f / 1024.0f);
  const float var = s2 * (1.0f / 1024.0f) - mean * mean;
  const float inv = rsqrtf(var + 1e-5f);
#pragma unroll
  for (int i = 0; i < 4; ++i) {
    const int c = tid + i * 256;
    const float y = (x[i] - mean) * inv * gw[c] + bw[c];
    hsb[(long long)r * 1024 + c] = f2b(y);
  }
}

// repack conv weights f32 [Cout][Cin][3][3] -> bf16 [Npad][9*Cin]
__global__ void repack_w(const float* __restrict__ src, u16* __restrict__ dst, int Cout, int l2c) {
  const int co = blockIdx.x, tid = threadIdx.x;
  const int Cin = 1 << l2c, K9 = 9 << l2c;
  for (int j = tid; j < K9; j += 256) {
    const int t = j >> l2c, ci = j & (Cin - 1);
    u16 v = 0;
    if (co < Cout) v = f2b(src[(long long)(co * Cin + ci) * 9 + t]);
    dst[(long long)co * K9 + j] = v;
  }
}

// bilinear x2 (half-pixel), bf16 NHWC -> bf16 NHWC (2H x 2W)
__global__ void ups2x(const u16* __restrict__ in, u16* __restrict__ out,
                      int l2h, int l2w, int l2c, long long total)
{
  const long long idx = (long long)blockIdx.x * 256 + threadIdx.x;
  if (idx >= total) return;
  const int H = 1 << l2h, W = 1 << l2w, C = 1 << l2c;
  const int c = (int)(idx & (C - 1));
  long long t = idx >> l2c;
  const int ox = (int)(t & (2 * W - 1)); t >>= (l2w + 1);
  const int oy = (int)(t & (2 * H - 1)); t >>= (l2h + 1);
  const int img = (int)t;
  const int iy = oy >> 1, ix = ox >> 1;
  int y0, y1, x0, x1; float wy0, wy1, wx0, wx1;
  if (oy & 1) { y0 = iy; y1 = min(iy + 1, H - 1); wy0 = 0.75f; wy1 = 0.25f; }
  else        { y0 = max(iy - 1, 0); y1 = iy;     wy0 = 0.25f; wy1 = 0.75f; }
  if (ox & 1) { x0 = ix; x1 = min(ix + 1, W - 1); wx0 = 0.75f; wx1 = 0.25f; }
  else        { x0 = max(ix - 1, 0); x1 = ix;     wx0 = 0.25f; wx1 = 0.75f; }
  const u16* base = in + (((long long)img) << (l2h + l2w + l2c));
  const float v00 = b2f(base[((((long long)y0 << l2w) + x0) << l2c) + c]);
  const float v01 = b2f(base[((((long long)y0 << l2w) + x1) << l2c) + c]);
  const float v10 = b2f(base[((((long long)y1 << l2w) + x0) << l2c) + c]);
  const float v11 = b2f(base[((((long long)y1 << l2w) + x1) << l2c) + c]);
  out[idx] = f2b(wy0 * (wx0 * v00 + wx1 * v01) + wy1 * (wx0 * v10 + wx1 * v11));
}

// 1x1 conv over 64 channels: C4 bf16 [262144][64] -> Z f32 [262144]
__global__ __launch_bounds__(256) void conv1x1_final(
    const u16* __restrict__ C4, const float* __restrict__ w5,
    const float* __restrict__ b5, float* __restrict__ Z)
{
  const int tid = threadIdx.x;
  const int px = blockIdx.x * 4 + (tid >> 6);
  const int lane = tid & 63;
  float v = b2f(C4[(long long)px * 64 + lane]) * w5[lane];
  for (int o = 32; o; o >>= 1) v += __shfl_down(v, o);
  if (lane == 0) Z[px] = v + b5[0];
}

// bilinear x2: Z f32 [64][64][64] -> out FLOAT32 [64][128][128]
__global__ void ups_final(const float* __restrict__ Z, float* __restrict__ out) {
  const int idx = blockIdx.x * 256 + threadIdx.x;
  const int ox = idx & 127, oy = (idx >> 7) & 127, img = idx >> 14;
  const int iy = oy >> 1, ix = ox >> 1;
  int y0, y1, x0, x1; float wy0, wy1, wx0, wx1;
  if (oy & 1) { y0 = iy; y1 = min(iy + 1, 63); wy0 = 0.75f; wy1 = 0.25f; }
  else        { y0 = max(iy - 1, 0); y1 = iy;  wy0 = 0.25f; wy1 = 0.75f; }
  if (ox & 1) { x0 = ix; x1 = min(ix + 1, 63); wx0 = 0.75f; wx1 = 0.25f; }
  else        { x0 = max(ix - 1, 0); x1 = ix;  wx0 = 0.25f; wx1 = 0.75f; }
  const float* zi = Z + (long long)img * 4096;
  const float v = wy0 * (wx0 * zi[y0 * 64 + x0] + wx1 * zi[y0 * 64 + x1]) +
                  wy1 * (wx0 * zi[y1 * 64 + x0] + wx1 * zi[y1 * 64 + x1]);
  out[idx] = v;
}

// ---------------------------------------------------------------------------
extern "C" void kernel_launch(void* const* d_in, const int* in_sizes, int n_in,
                              void* d_out, int out_size, void* d_ws, size_t ws_size,
                              hipStream_t stream)
{
  (void)in_sizes; (void)n_in; (void)out_size;
  if (ws_size < 110395648u) return;   // diagnostic: zero output => ws too small
  const float* patches = (const float*)d_in[0];
  const float* pe_w = (const float*)d_in[1];
  const float* pe_b = (const float*)d_in[2];
  const float* qkv_w = (const float*)d_in[3];
  const float* qkv_b = (const float*)d_in[4];
  const float* out_w = (const float*)d_in[5];
  const float* out_b = (const float*)d_in[6];
  const float* ln1_g = (const float*)d_in[7];
  const float* ln1_b = (const float*)d_in[8];
  const float* ff1_w = (const float*)d_in[9];
  const float* ff1_b = (const float*)d_in[10];
  const float* ff2_w = (const float*)d_in[11];
  const float* ff2_b = (const float*)d_in[12];
  const float* ln2_g = (const float*)d_in[13];
  const float* ln2_b = (const float*)d_in[14];
  const float* dwv[4] = {(const float*)d_in[15], (const float*)d_in[21], (const float*)d_in[27], (const float*)d_in[33]};
  const float* dbv[4] = {(const float*)d_in[16], (const float*)d_in[22], (const float*)d_in[28], (const float*)d_in[34]};
  const float* gv[4]  = {(const float*)d_in[17], (const float*)d_in[23], (const float*)d_in[29], (const float*)d_in[35]};
  const float* bev[4] = {(const float*)d_in[18], (const float*)d_in[24], (const float*)d_in[30], (const float*)d_in[36]};
  const float* mv[4]  = {(const float*)d_in[19], (const float*)d_in[25], (const float*)d_in[31], (const float*)d_in[37]};
  const float* vv[4]  = {(const float*)d_in[20], (const float*)d_in[26], (const float*)d_in[32], (const float*)d_in[38]};
  const float* dw5 = (const float*)d_in[39];
  const float* db5 = (const float*)d_in[40];
  float* outp = (float*)d_out;     // reference output dtype = float32
  char* ws = (char*)d_ws;

  // ---- workspace layout: rich sequential, peak 110,395,648 B --------------
  // transformer phase
  u16* HS_B = (u16*)(ws + 0);              // [4096][1024]
  u16* APE  = (u16*)(ws + 8388608);        // [4096][768] (dead before QKV)
  u16* QKV  = (u16*)(ws + 8388608);        // [4096][3072]   ends 33,554,432
  u16* VT   = (u16*)(ws + 33554432);       // [64][128][512] ends 41,943,040
  u16* SF   = (u16*)(ws + 41943040);       // [64][512][512] ends 75,497,472
  u16* FF1G = (u16*)(ws + 41943040);       // [4096][4096] (over dead SF)
  u16* ATT  = (u16*)(ws + 75497472);       // [4096][1024]   ends 83,886,080
  u16* P_B  = (u16*)(ws + 83886080);       // [4096][1024]   ends 92,274,688
  u16* W1   = (u16*)(ws + 92274688);       // 8.39M slot     ends 100,663,296
  u16* W2   = (u16*)(ws + 100663296);      // 8.39M slot     ends 109,051,904
  // decoder phase (all transformer buffers except HS_B dead)
  u16* WR1 = (u16*)(ws + 8388608);         // [512][9216]    ends 17,825,792
  u16* WR2 = (u16*)(ws + 17825792);        // [256][4608]    ends 20,185,088
  u16* WR3 = (u16*)(ws + 20185088);        // [128][2304]    ends 20,774,912
  u16* C1  = (u16*)(ws + 20774912);        // [4096][512]    ends 24,969,216
  u16* U1  = (u16*)(ws + 24969216);        // [64][16][16][512] ends 41,746,432
  u16* C2  = (u16*)(ws + 41746432);        // [16384][256]   ends 50,135,040
  u16* U2  = (u16*)(ws + 50135040);        // [64][32][32][256] ends 83,689,472
  u16* C3  = (u16*)(ws + 83689472);        // [65536][128]   ends 100,466,688
  u16* U3  = (u16*)(ws + 8388608);         // [64][64][64][128] ends 75,497,472 (over dead WR1-3/C1/U1/C2/U2)
  u16* C4  = (u16*)(ws + 75497472);        // [262144][64]   ends 109,051,904 (over dead C3/W-slots)
  u16* ZPG = (u16*)(ws + 109051904);       // 256 B zero page (live through all convs)
  u16* WR4 = (u16*)(ws + 109052160);       // [128][1152]    ends 109,347,072
  float* Z = (float*)(ws + 109347072);     // [262144] f32   ends 110,395,648

  // ---- patch embedding ----------------------------------------------------
  pe_gather<<<4096, 256, 0, stream>>>(patches, APE);
  cvt_f2b<<<768, 256, 0, stream>>>(pe_w, W1, 786432);
  gemm_bt<<<dim3(8, 32, 1), 256, 0, stream>>>(
      APE, 768, 0, 0, W1, 768, 0, 0,
      HS_B, 1024, 0, 0, pe_b, 0, 1, 24);

  // ---- transformer --------------------------------------------------------
  for (int l = 0; l < 2; ++l) {
    cvt_f2b<<<3072, 256, 0, stream>>>(qkv_w + (long long)l * 3145728, W1, 3145728);
    gemm_bt<<<dim3(24, 32, 1), 256, 0, stream>>>(
        HS_B, 1024, 0, 0, W1, 1024, 0, 0,
        QKV, 3072, 0, 0, qkv_b + l * 3072, 0, 1, 32);
    vt_transpose<<<dim3(8, 64), 256, 0, stream>>>(QKV, VT);
    // S = Q K^T for all 64 (batch,head)
    gemm_bt<<<dim3(4, 4, 64), 256, 0, stream>>>(
        QKV, 3072, 1572864, 128, QKV + 1024, 3072, 1572864, 128,
        SF, 512, 2097152, 262144, nullptr, 0, 8, 4);
    softmax_rows<<<32768, 256, 0, stream>>>(SF);
    // O = P V
    gemm_bt<<<dim3(1, 4, 64), 256, 0, stream>>>(
        SF, 512, 2097152, 262144, VT, 512, 524288, 65536,
        ATT, 1024, 524288, 128, nullptr, 0, 8, 16);
    cvt_f2b<<<1024, 256, 0, stream>>>(out_w + (long long)l * 1048576, W2, 1048576);
    gemm_bt<<<dim3(8, 32, 1), 256, 0, stream>>>(
        ATT, 1024, 0, 0, W2, 1024, 0, 0,
        P_B, 1024, 0, 0, out_b + l * 1024, 0, 1, 32);
    ln_kernel<<<4096, 256, 0, stream>>>(HS_B, P_B, ln1_g + l * 1024, ln1_b + l * 1024);
    cvt_f2b<<<4096, 256, 0, stream>>>(ff1_w + (long long)l * 4194304, W1, 4194304);
    cvt_f2b<<<4096, 256, 0, stream>>>(ff2_w + (long long)l * 4194304, W2, 4194304);
    gemm_bt<<<dim3(32, 32, 1), 256, 0, stream>>>(
        HS_B, 1024, 0, 0, W1, 1024, 0, 0,
        FF1G, 4096, 0, 0, ff1_b + l * 4096, 1, 1, 32);
    gemm_bt<<<dim3(8, 32, 1), 256, 0, stream>>>(
        FF1G, 4096, 0, 0, W2, 4096, 0, 0,
        P_B, 1024, 0, 0, ff2_b + l * 1024, 0, 1, 128);
    ln_kernel<<<4096, 256, 0, stream>>>(HS_B, P_B, ln2_g + l * 1024, ln2_b + l * 1024);
  }

  // ---- CNN decoder --------------------------------------------------------
  hipMemsetAsync((void*)ZPG, 0, 256, stream);
  repack_w<<<512, 256, 0, stream>>>(dwv[0], WR1, 512, 10);
  repack_w<<<256, 256, 0, stream>>>(dwv[1], WR2, 256, 9);
  repack_w<<<128, 256, 0, stream>>>(dwv[2], WR3, 128, 8);
  repack_w<<<128, 256, 0, stream>>>(dwv[3], WR4, 64, 7);

  conv_gemm<<<dim3(8, 32, 1), 256, 0, stream>>>(
      HS_B, WR1, C1, gv[0], bev[0], mv[0], vv[0], dbv[0], ZPG,
      8, 8, 3, 6, 10, 512, 9216, 288);
  ups2x<<<32768, 256, 0, stream>>>(C1, U1, 3, 3, 9, 8388608LL);
  conv_gemm<<<dim3(4, 128, 1), 256, 0, stream>>>(
      U1, WR2, C2, gv[1], bev[1], mv[1], vv[1], dbv[1], ZPG,
      16, 16, 4, 8, 9, 256, 4608, 144);
  ups2x<<<65536, 256, 0, stream>>>(C2, U2, 4, 4, 8, 16777216LL);
  conv_gemm<<<dim3(2, 512, 1), 256, 0, stream>>>(
      U2, WR3, C3, gv[2], bev[2], mv[2], vv[2], dbv[2], ZPG,
      32, 32, 5, 10, 8, 128, 2304, 72);
  ups2x<<<131072, 256, 0, stream>>>(C3, U3, 5, 5, 7, 33554432LL);
  conv_gemm<<<dim3(1, 2048, 1), 256, 0, stream>>>(
      U3, WR4, C4, gv[3], bev[3], mv[3], vv[3], dbv[3], ZPG,
      64, 64, 6, 12, 7, 64, 1152, 36);
  conv1x1_final<<<65536, 256, 0, stream>>>(C4, dw5, db5, Z);
  ups_final<<<4096, 256, 0, stream>>>(Z, outp);
}

// Round 3
// 1396.154 us; speedup vs baseline: 1.0768x; 1.0444x over previous
//
#include <hip/hip_runtime.h>
#include <stdint.h>

// ---------------------------------------------------------------------------
// LocalDino forward on MI355X (gfx950).
// Inputs: float32. OUTPUT: float32 (reference dtype). Internal: bf16 + f32 acc.
// Heavy math via mfma_f32_16x16x32_bf16. BOTH gemm_bt and conv_gemm now use:
//   - triple-buffered counted-vmcnt software pipeline (stage t+2 while
//     computing t; raw s_barrier, never vmcnt(0) in steady state)
//   - conflict-free XOR-swizzled LDS (linear global_load_lds dest + permuted
//     GLOBAL source + matching permuted read; R2 verified conflicts -> 0)
// conv grid puts M on blockIdx.x so the n-blocks sharing an A-panel co-reside
// on one XCD (R2 showed 252 MB L2-fill from cross-XCD A duplication).
// Rich sequential workspace layout, NO chunking, peak 110,395,648 B.
// ---------------------------------------------------------------------------

typedef unsigned short u16;
typedef __bf16 bf16x8 __attribute__((ext_vector_type(8)));
typedef short  s16x8  __attribute__((ext_vector_type(8)));
typedef float  f32x4  __attribute__((ext_vector_type(4)));

__device__ __forceinline__ float b2f(u16 x) { return __uint_as_float(((unsigned)x) << 16); }
__device__ __forceinline__ u16 f2b(float f) {
  unsigned u = __float_as_uint(f);
  unsigned r = (u + 0x7fffu + ((u >> 16) & 1u)) >> 16;   // RNE
  return (u16)r;
}
__device__ __forceinline__ void async16(u16* lds, const u16* g) {
  __builtin_amdgcn_global_load_lds((const __attribute__((address_space(1))) void*)g,
                                   (__attribute__((address_space(3))) void*)lds, 16, 0, 0);
}
__device__ __forceinline__ float gelu_f(float x) {
  return 0.5f * x * (1.0f + erff(x * 0.70710678118654752f));  // exact gelu
}

// f32 -> bf16 canonicalization
__global__ __launch_bounds__(256) void cvt_f2b(const float* __restrict__ src,
                                               u16* __restrict__ dst, int n) {
  const int i = (blockIdx.x * 256 + threadIdx.x) * 4;
  if (i + 3 < n) {
    const float4 v = *(const float4*)(src + i);
    dst[i] = f2b(v.x); dst[i + 1] = f2b(v.y); dst[i + 2] = f2b(v.z); dst[i + 3] = f2b(v.w);
  }
}

// ---------------------------------------------------------------------------
// bf16 GEMM: C[m,n] = sum_k A[m,k]*B[n,k] (+bias[n]) (+gelu). Cb bf16 output.
// Batched via blockIdx.z: off = (z/ZH)*s?b + (z%ZH)*s?h.
// Triple-buffered counted-vmcnt pipeline (4 async16/stage -> vmcnt 8/4/0)
// + XOR-swizzled LDS (k-chunk lq of row r at slot lq ^ ((r>>1)&3)).
// Works for any nk >= 1 (rolling buffer index, no unroll-by-3 constraint).
// ---------------------------------------------------------------------------
__global__ __launch_bounds__(256) void gemm_bt(
    const u16* __restrict__ A, int lda, long long sAb, long long sAh,
    const u16* __restrict__ B, int ldb, long long sBb, long long sBh,
    u16* __restrict__ Cb, int ldc, long long sCb, long long sCh,
    const float* __restrict__ bias, int epi, int ZH, int nk)
{
  __shared__ u16 As[3][128 * 32];
  __shared__ u16 Bs[3][128 * 32];
  const int tid = threadIdx.x;
  const int zb = blockIdx.z / ZH, zh = blockIdx.z % ZH;
  const u16* Ab = A + zb * sAb + zh * sAh;
  const u16* Bb = B + zb * sBb + zh * sBh;
  const int m0 = blockIdx.y << 7, n0 = blockIdx.x << 7;
  const int wave = tid >> 6, lane = tid & 63;
  const int wm = (wave >> 1) << 6, wn = (wave & 1) << 6;
  const int lr = lane & 15, lq = lane >> 4;
  const int rowb = tid >> 2;
  // swizzled k-chunk this thread stages (rows rowb and rowb+64 share
  // (row>>1)&3 since 64>>1 = 32 == 0 mod 4):
  const int kc_e = (((tid & 3) ^ ((tid >> 3) & 3)) << 3);
  // swizzled LDS element offset for fragment reads:
  const int kslot = ((lq ^ ((lr >> 1) & 3)) << 3);

  const u16* Arow0 = Ab + (long long)(m0 + rowb)      * lda + kc_e;
  const u16* Arow1 = Ab + (long long)(m0 + rowb + 64) * lda + kc_e;
  const u16* Brow0 = Bb + (long long)(n0 + rowb)      * ldb + kc_e;
  const u16* Brow1 = Bb + (long long)(n0 + rowb + 64) * ldb + kc_e;

  f32x4 acc[4][4] = {};

  auto stage = [&](int kt, int b) {
    const int k0 = kt << 5;
    async16(&As[b][tid * 8],         Arow0 + k0);
    async16(&As[b][(tid + 256) * 8], Arow1 + k0);
    async16(&Bs[b][tid * 8],         Brow0 + k0);
    async16(&Bs[b][(tid + 256) * 8], Brow1 + k0);
  };

  stage(0, 0);
  if (nk > 1) stage(1, 1);
  int cur = 0;
  for (int kt = 0; kt < nk; ++kt) {
    if (kt + 2 < nk) {
      int nb = cur + 2; if (nb >= 3) nb -= 3;
      stage(kt + 2, nb);   // buffer last read at tile kt-1; trailing barrier
                           // of phase kt-1 ordered those ds_reads before this.
      // 12 loads in flight (tiles kt..kt+2); wait to <=8 so tile kt landed.
      asm volatile("s_waitcnt vmcnt(8)" ::: "memory");
    } else if (kt + 1 < nk) {
      asm volatile("s_waitcnt vmcnt(4)" ::: "memory");
    } else {
      asm volatile("s_waitcnt vmcnt(0)" ::: "memory");
    }
    asm volatile("s_barrier" ::: "memory");   // publish tile kt to all waves

    bf16x8 af[4], bfv[4];
#pragma unroll
    for (int mi = 0; mi < 4; ++mi)
      af[mi] = __builtin_bit_cast(bf16x8, *(const s16x8*)&As[cur][((wm + mi * 16 + lr) << 5) + kslot]);
#pragma unroll
    for (int ni = 0; ni < 4; ++ni)
      bfv[ni] = __builtin_bit_cast(bf16x8, *(const s16x8*)&Bs[cur][((wn + ni * 16 + lr) << 5) + kslot]);
#pragma unroll
    for (int mi = 0; mi < 4; ++mi)
#pragma unroll
      for (int ni = 0; ni < 4; ++ni)
        acc[mi][ni] = __builtin_amdgcn_mfma_f32_16x16x32_bf16(af[mi], bfv[ni], acc[mi][ni], 0, 0, 0);

    asm volatile("s_barrier" ::: "memory");   // protect buffer cur
    ++cur; if (cur == 3) cur = 0;
  }

  const long long Co = zb * sCb + zh * sCh;
#pragma unroll
  for (int ni = 0; ni < 4; ++ni) {
    const int col = n0 + wn + ni * 16 + lr;
    const float badd = bias ? bias[col] : 0.0f;
#pragma unroll
    for (int mi = 0; mi < 4; ++mi) {
      const int row0 = m0 + wm + mi * 16 + (lq << 2);
#pragma unroll
      for (int r = 0; r < 4; ++r) {
        float v = acc[mi][ni][r] + badd;
        if (epi == 1) v = gelu_f(v);
        Cb[Co + (long long)(row0 + r) * ldc + col] = f2b(v);
      }
    }
  }
}

// ---------------------------------------------------------------------------
// Implicit-GEMM conv3x3 SAME, NHWC bf16 in, fused BN(eval)+ReLU, bf16 out.
// K = 9*Cin as ((dy*3+dx)*Cin + ci). Wr: [Npad x K] bf16. OOB -> zero page.
// Tile 128(M on blockIdx.x!) x 64(N on blockIdx.y): XCD = linear%8 = m%8, so
// all n-blocks sharing an A-panel co-reside on one XCD -> A im2col stream is
// fetched into that XCD's L2 once (R2: cross-XCD duplication cost 252 MB).
// Triple-buffered counted-vmcnt pipeline (3 async16/stage -> vmcnt 6/3/0)
// + XOR-swizzled LDS (verified conflict-free in R2). nk % 3 == 0.
// ---------------------------------------------------------------------------
__global__ __launch_bounds__(256) void conv_gemm(
    const u16* __restrict__ U, const u16* __restrict__ Wr,
    u16* __restrict__ Out,
    const float* __restrict__ bn_g, const float* __restrict__ bn_b,
    const float* __restrict__ bn_m, const float* __restrict__ bn_v,
    const float* __restrict__ cb,
    const u16* __restrict__ zpg,
    int H, int W, int l2w, int l2hw, int l2c, int CoutReal, int Kdim, int nk)
{
  __shared__ u16 As[3][128 * 32];   // 8 KB per buffer
  __shared__ u16 Bs[3][64 * 32];    // 4 KB per buffer
  const int tid = threadIdx.x;
  const int m0 = blockIdx.x << 7, n0 = blockIdx.y << 6;   // M on x (XCD share)
  const int wave = tid >> 6, lane = tid & 63;
  const int wm = (wave >> 1) << 6, wn = (wave & 1) << 5;
  const int lr = lane & 15, lq = lane >> 4;
  const int rowb = tid >> 2;
  const int kc_e = (((tid & 3) ^ ((tid >> 3) & 3)) << 3);
  const int kslot = ((lq ^ ((lr >> 1) & 3)) << 3);
  const int hwmask = (1 << l2hw) - 1, wmask = (1 << l2w) - 1, cmask = (1 << l2c) - 1;

  // Per-thread A-row geometry (phase-invariant): two halves i=0,1.
  int yA[2], xA[2];
  long long baseA[2];
  {
#pragma unroll
    for (int i = 0; i < 2; ++i) {
      const int mrow = m0 + rowb + (i << 6);
      const int img = mrow >> l2hw;
      const int rem = mrow & hwmask;
      yA[i] = rem >> l2w; xA[i] = rem & wmask;
      baseA[i] = (long long)(img << l2hw);
    }
  }
  const u16* Bbase = Wr + (long long)(n0 + rowb) * Kdim + kc_e;

  f32x4 acc[4][2] = {};

  // Stage k-tile kt into buffer b: exactly 3 async16 per thread (2 A + 1 B).
  auto stage = [&](int kt, int b) {
    const int k0 = kt << 5;
    const int k = k0 + kc_e;
    const int t = k >> l2c, ci = k & cmask;
    const int dy = (t * 86) >> 8;   // t/3 for t in [0,8]
    const int dx = t - dy * 3;
#pragma unroll
    for (int i = 0; i < 2; ++i) {
      const int yy = yA[i] + dy - 1, xx = xA[i] + dx - 1;
      const u16* src = ((unsigned)yy < (unsigned)H && (unsigned)xx < (unsigned)W)
          ? U + (((baseA[i] + (yy << l2w) + xx) << l2c) + ci)
          : zpg;
      async16(&As[b][(tid + (i << 8)) * 8], src);
    }
    async16(&Bs[b][tid * 8], Bbase + k0);
  };

  // Prologue: tiles 0 and 1 in flight (6 loads/thread outstanding).
  stage(0, 0);
  stage(1, 1);

  for (int t0 = 0; t0 < nk; t0 += 3) {
#pragma unroll
    for (int p = 0; p < 3; ++p) {
      const int tt = t0 + p;
      if (tt + 2 < nk) {
        stage(tt + 2, (p + 2) % 3);
        asm volatile("s_waitcnt vmcnt(6)" ::: "memory");
      } else if (tt + 1 < nk) {
        asm volatile("s_waitcnt vmcnt(3)" ::: "memory");
      } else {
        asm volatile("s_waitcnt vmcnt(0)" ::: "memory");
      }
      asm volatile("s_barrier" ::: "memory");   // publish tile tt

      bf16x8 af[4], bfv[2];
#pragma unroll
      for (int mi = 0; mi < 4; ++mi)
        af[mi] = __builtin_bit_cast(bf16x8, *(const s16x8*)&As[p][((wm + mi * 16 + lr) << 5) + kslot]);
#pragma unroll
      for (int ni = 0; ni < 2; ++ni)
        bfv[ni] = __builtin_bit_cast(bf16x8, *(const s16x8*)&Bs[p][((wn + ni * 16 + lr) << 5) + kslot]);
#pragma unroll
      for (int mi = 0; mi < 4; ++mi)
#pragma unroll
        for (int ni = 0; ni < 2; ++ni)
          acc[mi][ni] = __builtin_amdgcn_mfma_f32_16x16x32_bf16(af[mi], bfv[ni], acc[mi][ni], 0, 0, 0);

      asm volatile("s_barrier" ::: "memory");   // protect buffer p
    }
  }

#pragma unroll
  for (int ni = 0; ni < 2; ++ni) {
    const int col = n0 + wn + ni * 16 + lr;
    const bool ok = col < CoutReal;
    float bs = 0.0f, bsh = 0.0f;
    if (ok) {
      const float inv = rsqrtf(bn_v[col] + 1e-5f);
      bs = bn_g[col] * inv;
      bsh = (cb[col] - bn_m[col]) * bs + bn_b[col];
    }
#pragma unroll
    for (int mi = 0; mi < 4; ++mi) {
      const int row0 = m0 + wm + mi * 16 + (lq << 2);
#pragma unroll
      for (int r = 0; r < 4; ++r) {
        if (ok) {
          const float v = fmaxf(acc[mi][ni][r] * bs + bsh, 0.0f);
          Out[(long long)(row0 + r) * CoutReal + col] = f2b(v);
        }
      }
    }
  }
}

// --------------------------- auxiliary kernels -----------------------------

// patches f32 [64][3][128][128] -> A_pe bf16 [4096 tok][768] (k=c*256+ky*16+kx)
__global__ void pe_gather(const float* __restrict__ patches, u16* __restrict__ Ape) {
  const int t = blockIdx.x, tid = threadIdx.x;
  const int img = t >> 6, pos = t & 63, ty = pos >> 3, tx = pos & 7;
  const float* base = patches + (long long)img * 3 * 128 * 128;
  u16* dst = Ape + (long long)t * 768;
  for (int k = tid; k < 768; k += 256) {
    const int c = k >> 8, rr = k & 255, ky = rr >> 4, kx = rr & 15;
    dst[k] = f2b(base[c * 16384 + (ty * 16 + ky) * 128 + tx * 16 + kx]);
  }
}

// V slice of qkv -> Vt [z=bq*8+h][128 d][512 t] bf16 (LDS transpose)
__global__ void vt_transpose(const u16* __restrict__ qkv, u16* __restrict__ Vt) {
  __shared__ u16 lds[64 * 130];
  const int tt = blockIdx.x;       // t-tile 0..7
  const int z = blockIdx.y;        // 0..63
  const int bq = z >> 3, h = z & 7;
  const int tid = threadIdx.x;
  for (int idx = tid; idx < 64 * 128; idx += 256) {
    const int t = idx >> 7, d = idx & 127;
    lds[t * 130 + d] = qkv[(long long)(bq * 512 + tt * 64 + t) * 3072 + 2048 + h * 128 + d];
  }
  __syncthreads();
  for (int idx = tid; idx < 64 * 128; idx += 256) {
    const int d = idx >> 6, t = idx & 63;
    Vt[(long long)z * 65536 + d * 512 + tt * 64 + t] = lds[t * 130 + d];
  }
}

// in-place row softmax with 1/sqrt(128) scale on bf16 rows of 512
__global__ __launch_bounds__(256) void softmax_rows(u16* __restrict__ P) {
  __shared__ float red[8];
  const long long base = (long long)blockIdx.x * 512;
  const int tid = threadIdx.x;
  const float sc = 0.08838834764831845f;
  float x0 = b2f(P[base + tid]) * sc;
  float x1 = b2f(P[base + tid + 256]) * sc;
  float mx = fmaxf(x0, x1);
  for (int o = 32; o; o >>= 1) mx = fmaxf(mx, __shfl_down(mx, o));
  if ((tid & 63) == 0) red[tid >> 6] = mx;
  __syncthreads();
  mx = fmaxf(fmaxf(red[0], red[1]), fmaxf(red[2], red[3]));
  const float e0 = expf(x0 - mx), e1 = expf(x1 - mx);
  float s = e0 + e1;
  for (int o = 32; o; o >>= 1) s += __shfl_down(s, o);
  __syncthreads();
  if ((tid & 63) == 0) red[tid >> 6] = s;
  __syncthreads();
  s = red[0] + red[1] + red[2] + red[3];
  const float inv = 1.0f / s;
  P[base + tid] = f2b(e0 * inv);
  P[base + tid + 256] = f2b(e1 * inv);
}

// hs_b = LN(hs_b + P; g,b).  P bf16.  One block per row of 1024.
__global__ __launch_bounds__(256) void ln_kernel(
    u16* __restrict__ hsb, const u16* __restrict__ P,
    const float* __restrict__ gw, const float* __restrict__ bw)
{
  __shared__ float red[8];
  const int r = blockIdx.x, tid = threadIdx.x;
  float x[4], s = 0.0f, s2 = 0.0f;
#pragma unroll
  for (int i = 0; i < 4; ++i) {
    const int c = tid + i * 256;
    const float v = b2f(hsb[(long long)r * 1024 + c]) + b2f(P[(long long)r * 1024 + c]);
    x[i] = v; s += v; s2 += v * v;
  }
  for (int o = 32; o; o >>= 1) { s += __shfl_down(s, o); s2 += __shfl_down(s2, o); }
  if ((tid & 63) == 0) { red[tid >> 6] = s; red[4 + (tid >> 6)] = s2; }
  __syncthreads();
  s  = red[0] + red[1] + red[2] + red[3];
  s2 = red[4] + red[5] + red[6] + red[7];
  const float mean = s * (1.0f / 1024.0f);
  const float var = s2 * (1.0f / 1024.0f) - mean * mean;
  const float inv = rsqrtf(var + 1e-5f);
#pragma unroll
  for (int i = 0; i < 4; ++i) {
    const int c = tid + i * 256;
    const float y = (x[i] - mean) * inv * gw[c] + bw[c];
    hsb[(long long)r * 1024 + c] = f2b(y);
  }
}

// repack conv weights f32 [Cout][Cin][3][3] -> bf16 [Npad][9*Cin]
__global__ void repack_w(const float* __restrict__ src, u16* __restrict__ dst, int Cout, int l2c) {
  const int co = blockIdx.x, tid = threadIdx.x;
  const int Cin = 1 << l2c, K9 = 9 << l2c;
  for (int j = tid; j < K9; j += 256) {
    const int t = j >> l2c, ci = j & (Cin - 1);
    u16 v = 0;
    if (co < Cout) v = f2b(src[(long long)(co * Cin + ci) * 9 + t]);
    dst[(long long)co * K9 + j] = v;
  }
}

// bilinear x2 (half-pixel), bf16 NHWC -> bf16 NHWC (2H x 2W)
__global__ void ups2x(const u16* __restrict__ in, u16* __restrict__ out,
                      int l2h, int l2w, int l2c, long long total)
{
  const long long idx = (long long)blockIdx.x * 256 + threadIdx.x;
  if (idx >= total) return;
  const int H = 1 << l2h, W = 1 << l2w, C = 1 << l2c;
  const int c = (int)(idx & (C - 1));
  long long t = idx >> l2c;
  const int ox = (int)(t & (2 * W - 1)); t >>= (l2w + 1);
  const int oy = (int)(t & (2 * H - 1)); t >>= (l2h + 1);
  const int img = (int)t;
  const int iy = oy >> 1, ix = ox >> 1;
  int y0, y1, x0, x1; float wy0, wy1, wx0, wx1;
  if (oy & 1) { y0 = iy; y1 = min(iy + 1, H - 1); wy0 = 0.75f; wy1 = 0.25f; }
  else        { y0 = max(iy - 1, 0); y1 = iy;     wy0 = 0.25f; wy1 = 0.75f; }
  if (ox & 1) { x0 = ix; x1 = min(ix + 1, W - 1); wx0 = 0.75f; wx1 = 0.25f; }
  else        { x0 = max(ix - 1, 0); x1 = ix;     wx0 = 0.25f; wx1 = 0.75f; }
  const u16* base = in + (((long long)img) << (l2h + l2w + l2c));
  const float v00 = b2f(base[((((long long)y0 << l2w) + x0) << l2c) + c]);
  const float v01 = b2f(base[((((long long)y0 << l2w) + x1) << l2c) + c]);
  const float v10 = b2f(base[((((long long)y1 << l2w) + x0) << l2c) + c]);
  const float v11 = b2f(base[((((long long)y1 << l2w) + x1) << l2c) + c]);
  out[idx] = f2b(wy0 * (wx0 * v00 + wx1 * v01) + wy1 * (wx0 * v10 + wx1 * v11));
}

// 1x1 conv over 64 channels: C4 bf16 [262144][64] -> Z f32 [262144]
__global__ __launch_bounds__(256) void conv1x1_final(
    const u16* __restrict__ C4, const float* __restrict__ w5,
    const float* __restrict__ b5, float* __restrict__ Z)
{
  const int tid = threadIdx.x;
  const int px = blockIdx.x * 4 + (tid >> 6);
  const int lane = tid & 63;
  float v = b2f(C4[(long long)px * 64 + lane]) * w5[lane];
  for (int o = 32; o; o >>= 1) v += __shfl_down(v, o);
  if (lane == 0) Z[px] = v + b5[0];
}

// bilinear x2: Z f32 [64][64][64] -> out FLOAT32 [64][128][128]
__global__ void ups_final(const float* __restrict__ Z, float* __restrict__ out) {
  const int idx = blockIdx.x * 256 + threadIdx.x;
  const int ox = idx & 127, oy = (idx >> 7) & 127, img = idx >> 14;
  const int iy = oy >> 1, ix = ox >> 1;
  int y0, y1, x0, x1; float wy0, wy1, wx0, wx1;
  if (oy & 1) { y0 = iy; y1 = min(iy + 1, 63); wy0 = 0.75f; wy1 = 0.25f; }
  else        { y0 = max(iy - 1, 0); y1 = iy;  wy0 = 0.25f; wy1 = 0.75f; }
  if (ox & 1) { x0 = ix; x1 = min(ix + 1, 63); wx0 = 0.75f; wx1 = 0.25f; }
  else        { x0 = max(ix - 1, 0); x1 = ix;  wx0 = 0.25f; wx1 = 0.75f; }
  const float* zi = Z + (long long)img * 4096;
  const float v = wy0 * (wx0 * zi[y0 * 64 + x0] + wx1 * zi[y0 * 64 + x1]) +
                  wy1 * (wx0 * zi[y1 * 64 + x0] + wx1 * zi[y1 * 64 + x1]);
  out[idx] = v;
}

// ---------------------------------------------------------------------------
extern "C" void kernel_launch(void* const* d_in, const int* in_sizes, int n_in,
                              void* d_out, int out_size, void* d_ws, size_t ws_size,
                              hipStream_t stream)
{
  (void)in_sizes; (void)n_in; (void)out_size;
  if (ws_size < 110395648u) return;   // diagnostic: zero output => ws too small
  const float* patches = (const float*)d_in[0];
  const float* pe_w = (const float*)d_in[1];
  const float* pe_b = (const float*)d_in[2];
  const float* qkv_w = (const float*)d_in[3];
  const float* qkv_b = (const float*)d_in[4];
  const float* out_w = (const float*)d_in[5];
  const float* out_b = (const float*)d_in[6];
  const float* ln1_g = (const float*)d_in[7];
  const float* ln1_b = (const float*)d_in[8];
  const float* ff1_w = (const float*)d_in[9];
  const float* ff1_b = (const float*)d_in[10];
  const float* ff2_w = (const float*)d_in[11];
  const float* ff2_b = (const float*)d_in[12];
  const float* ln2_g = (const float*)d_in[13];
  const float* ln2_b = (const float*)d_in[14];
  const float* dwv[4] = {(const float*)d_in[15], (const float*)d_in[21], (const float*)d_in[27], (const float*)d_in[33]};
  const float* dbv[4] = {(const float*)d_in[16], (const float*)d_in[22], (const float*)d_in[28], (const float*)d_in[34]};
  const float* gv[4]  = {(const float*)d_in[17], (const float*)d_in[23], (const float*)d_in[29], (const float*)d_in[35]};
  const float* bev[4] = {(const float*)d_in[18], (const float*)d_in[24], (const float*)d_in[30], (const float*)d_in[36]};
  const float* mv[4]  = {(const float*)d_in[19], (const float*)d_in[25], (const float*)d_in[31], (const float*)d_in[37]};
  const float* vv[4]  = {(const float*)d_in[20], (const float*)d_in[26], (const float*)d_in[32], (const float*)d_in[38]};
  const float* dw5 = (const float*)d_in[39];
  const float* db5 = (const float*)d_in[40];
  float* outp = (float*)d_out;     // reference output dtype = float32
  char* ws = (char*)d_ws;

  // ---- workspace layout: rich sequential, peak 110,395,648 B --------------
  // transformer phase
  u16* HS_B = (u16*)(ws + 0);              // [4096][1024]
  u16* APE  = (u16*)(ws + 8388608);        // [4096][768] (dead before QKV)
  u16* QKV  = (u16*)(ws + 8388608);        // [4096][3072]   ends 33,554,432
  u16* VT   = (u16*)(ws + 33554432);       // [64][128][512] ends 41,943,040
  u16* SF   = (u16*)(ws + 41943040);       // [64][512][512] ends 75,497,472
  u16* FF1G = (u16*)(ws + 41943040);       // [4096][4096] (over dead SF)
  u16* ATT  = (u16*)(ws + 75497472);       // [4096][1024]   ends 83,886,080
  u16* P_B  = (u16*)(ws + 83886080);       // [4096][1024]   ends 92,274,688
  u16* W1   = (u16*)(ws + 92274688);       // 8.39M slot     ends 100,663,296
  u16* W2   = (u16*)(ws + 100663296);      // 8.39M slot     ends 109,051,904
  // decoder phase (all transformer buffers except HS_B dead)
  u16* WR1 = (u16*)(ws + 8388608);         // [512][9216]    ends 17,825,792
  u16* WR2 = (u16*)(ws + 17825792);        // [256][4608]    ends 20,185,088
  u16* WR3 = (u16*)(ws + 20185088);        // [128][2304]    ends 20,774,912
  u16* C1  = (u16*)(ws + 20774912);        // [4096][512]    ends 24,969,216
  u16* U1  = (u16*)(ws + 24969216);        // [64][16][16][512] ends 41,746,432
  u16* C2  = (u16*)(ws + 41746432);        // [16384][256]   ends 50,135,040
  u16* U2  = (u16*)(ws + 50135040);        // [64][32][32][256] ends 83,689,472
  u16* C3  = (u16*)(ws + 83689472);        // [65536][128]   ends 100,466,688
  u16* U3  = (u16*)(ws + 8388608);         // [64][64][64][128] ends 75,497,472 (over dead WR1-3/C1/U1/C2/U2)
  u16* C4  = (u16*)(ws + 75497472);        // [262144][64]   ends 109,051,904 (over dead C3/W-slots)
  u16* ZPG = (u16*)(ws + 109051904);       // 256 B zero page (live through all convs)
  u16* WR4 = (u16*)(ws + 109052160);       // [128][1152]    ends 109,347,072
  float* Z = (float*)(ws + 109347072);     // [262144] f32   ends 110,395,648

  // ---- patch embedding ----------------------------------------------------
  pe_gather<<<4096, 256, 0, stream>>>(patches, APE);
  cvt_f2b<<<768, 256, 0, stream>>>(pe_w, W1, 786432);
  gemm_bt<<<dim3(8, 32, 1), 256, 0, stream>>>(
      APE, 768, 0, 0, W1, 768, 0, 0,
      HS_B, 1024, 0, 0, pe_b, 0, 1, 24);

  // ---- transformer --------------------------------------------------------
  for (int l = 0; l < 2; ++l) {
    cvt_f2b<<<3072, 256, 0, stream>>>(qkv_w + (long long)l * 3145728, W1, 3145728);
    gemm_bt<<<dim3(24, 32, 1), 256, 0, stream>>>(
        HS_B, 1024, 0, 0, W1, 1024, 0, 0,
        QKV, 3072, 0, 0, qkv_b + l * 3072, 0, 1, 32);
    vt_transpose<<<dim3(8, 64), 256, 0, stream>>>(QKV, VT);
    // S = Q K^T for all 64 (batch,head)
    gemm_bt<<<dim3(4, 4, 64), 256, 0, stream>>>(
        QKV, 3072, 1572864, 128, QKV + 1024, 3072, 1572864, 128,
        SF, 512, 2097152, 262144, nullptr, 0, 8, 4);
    softmax_rows<<<32768, 256, 0, stream>>>(SF);
    // O = P V
    gemm_bt<<<dim3(1, 4, 64), 256, 0, stream>>>(
        SF, 512, 2097152, 262144, VT, 512, 524288, 65536,
        ATT, 1024, 524288, 128, nullptr, 0, 8, 16);
    cvt_f2b<<<1024, 256, 0, stream>>>(out_w + (long long)l * 1048576, W2, 1048576);
    gemm_bt<<<dim3(8, 32, 1), 256, 0, stream>>>(
        ATT, 1024, 0, 0, W2, 1024, 0, 0,
        P_B, 1024, 0, 0, out_b + l * 1024, 0, 1, 32);
    ln_kernel<<<4096, 256, 0, stream>>>(HS_B, P_B, ln1_g + l * 1024, ln1_b + l * 1024);
    cvt_f2b<<<4096, 256, 0, stream>>>(ff1_w + (long long)l * 4194304, W1, 4194304);
    cvt_f2b<<<4096, 256, 0, stream>>>(ff2_w + (long long)l * 4194304, W2, 4194304);
    gemm_bt<<<dim3(32, 32, 1), 256, 0, stream>>>(
        HS_B, 1024, 0, 0, W1, 1024, 0, 0,
        FF1G, 4096, 0, 0, ff1_b + l * 4096, 1, 1, 32);
    gemm_bt<<<dim3(8, 32, 1), 256, 0, stream>>>(
        FF1G, 4096, 0, 0, W2, 4096, 0, 0,
        P_B, 1024, 0, 0, ff2_b + l * 1024, 0, 1, 128);
    ln_kernel<<<4096, 256, 0, stream>>>(HS_B, P_B, ln2_g + l * 1024, ln2_b + l * 1024);
  }

  // ---- CNN decoder --------------------------------------------------------
  hipMemsetAsync((void*)ZPG, 0, 256, stream);
  repack_w<<<512, 256, 0, stream>>>(dwv[0], WR1, 512, 10);
  repack_w<<<256, 256, 0, stream>>>(dwv[1], WR2, 256, 9);
  repack_w<<<128, 256, 0, stream>>>(dwv[2], WR3, 128, 8);
  repack_w<<<128, 256, 0, stream>>>(dwv[3], WR4, 64, 7);

  conv_gemm<<<dim3(32, 8, 1), 256, 0, stream>>>(
      HS_B, WR1, C1, gv[0], bev[0], mv[0], vv[0], dbv[0], ZPG,
      8, 8, 3, 6, 10, 512, 9216, 288);
  ups2x<<<32768, 256, 0, stream>>>(C1, U1, 3, 3, 9, 8388608LL);
  conv_gemm<<<dim3(128, 4, 1), 256, 0, stream>>>(
      U1, WR2, C2, gv[1], bev[1], mv[1], vv[1], dbv[1], ZPG,
      16, 16, 4, 8, 9, 256, 4608, 144);
  ups2x<<<65536, 256, 0, stream>>>(C2, U2, 4, 4, 8, 16777216LL);
  conv_gemm<<<dim3(512, 2, 1), 256, 0, stream>>>(
      U2, WR3, C3, gv[2], bev[2], mv[2], vv[2], dbv[2], ZPG,
      32, 32, 5, 10, 8, 128, 2304, 72);
  ups2x<<<131072, 256, 0, stream>>>(C3, U3, 5, 5, 7, 33554432LL);
  conv_gemm<<<dim3(2048, 1, 1), 256, 0, stream>>>(
      U3, WR4, C4, gv[3], bev[3], mv[3], vv[3], dbv[3], ZPG,
      64, 64, 6, 12, 7, 64, 1152, 36);
  conv1x1_final<<<65536, 256, 0, stream>>>(C4, dw5, db5, Z);
  ups_final<<<4096, 256, 0, stream>>>(Z, outp);
}

// Round 5
// 1305.767 us; speedup vs baseline: 1.1514x; 1.0692x over previous
//
#include <hip/hip_runtime.h>
#include <stdint.h>

// ---------------------------------------------------------------------------
// LocalDino forward on MI355X (gfx950).
// Inputs: float32. OUTPUT: float32 (reference dtype). Internal: bf16 + f32 acc.
// Heavy math via mfma_f32_16x16x32_bf16. gemm_bt and conv_gemm use:
//   - triple-buffered counted-vmcnt software pipeline
//   - conflict-free XOR-swizzled LDS (R2 verified conflicts -> 0)
//   - SPLIT-K (R3: conv1 pinned at 146us across wildly different memory
//     behavior => latency-bound at 1 block/CU; fix = more blocks/CU).
// Decoder workspace layout REVERTED to the R3-verified one (R4's relayout
// had C4 overlap live U3 -> race). Partials live in audited dead regions.
// conv grid keeps M on blockIdx.x (R3: fetch 252->41 MB from XCD A-sharing).
// ---------------------------------------------------------------------------

typedef unsigned short u16;
typedef __bf16 bf16x8 __attribute__((ext_vector_type(8)));
typedef short  s16x8  __attribute__((ext_vector_type(8)));
typedef float  f32x4  __attribute__((ext_vector_type(4)));

__device__ __forceinline__ float b2f(u16 x) { return __uint_as_float(((unsigned)x) << 16); }
__device__ __forceinline__ u16 f2b(float f) {
  unsigned u = __float_as_uint(f);
  unsigned r = (u + 0x7fffu + ((u >> 16) & 1u)) >> 16;   // RNE
  return (u16)r;
}
__device__ __forceinline__ void async16(u16* lds, const u16* g) {
  __builtin_amdgcn_global_load_lds((const __attribute__((address_space(1))) void*)g,
                                   (__attribute__((address_space(3))) void*)lds, 16, 0, 0);
}
__device__ __forceinline__ float gelu_f(float x) {
  return 0.5f * x * (1.0f + erff(x * 0.70710678118654752f));  // exact gelu
}

// f32 -> bf16 canonicalization
__global__ __launch_bounds__(256) void cvt_f2b(const float* __restrict__ src,
                                               u16* __restrict__ dst, int n) {
  const int i = (blockIdx.x * 256 + threadIdx.x) * 4;
  if (i + 3 < n) {
    const float4 v = *(const float4*)(src + i);
    dst[i] = f2b(v.x); dst[i + 1] = f2b(v.y); dst[i + 2] = f2b(v.z); dst[i + 3] = f2b(v.w);
  }
}

// ---------------------------------------------------------------------------
// bf16 GEMM: C[m,n] = sum_k A[m,k]*B[n,k] (+bias[n]) (+gelu). Cb bf16 output.
// Batched via blockIdx.z: off = (z/ZH)*s?b + (z%ZH)*s?h.
// SPLIT-K mode: Part != nullptr -> blockIdx.z = k-slice (ZH must be 1);
// slice covers k-tiles [z*nk, (z+1)*nk); writes f32 partial at
// Part + z*sCb + row*ldc + col (bias/epilogue applied by reduce_bias).
// ---------------------------------------------------------------------------
__global__ __launch_bounds__(256) void gemm_bt(
    const u16* __restrict__ A, int lda, long long sAb, long long sAh,
    const u16* __restrict__ B, int ldb, long long sBb, long long sBh,
    u16* __restrict__ Cb, int ldc, long long sCb, long long sCh,
    const float* __restrict__ bias, int epi, int ZH, int nk,
    float* __restrict__ Part)
{
  __shared__ u16 As[3][128 * 32];
  __shared__ u16 Bs[3][128 * 32];
  const int tid = threadIdx.x;
  const int zb = blockIdx.z / ZH, zh = blockIdx.z % ZH;
  const u16* Ab = A + zb * sAb + zh * sAh;
  const u16* Bb = B + zb * sBb + zh * sBh;
  const int m0 = blockIdx.y << 7, n0 = blockIdx.x << 7;
  const int wave = tid >> 6, lane = tid & 63;
  const int wm = (wave >> 1) << 6, wn = (wave & 1) << 6;
  const int lr = lane & 15, lq = lane >> 4;
  const int rowb = tid >> 2;
  const int koff = Part ? (zb * (nk << 5)) : 0;   // k-slice element offset
  // swizzled k-chunk this thread stages (rows rowb and rowb+64 share
  // (row>>1)&3):
  const int kc_e = (((tid & 3) ^ ((tid >> 3) & 3)) << 3);
  // swizzled LDS element offset for fragment reads:
  const int kslot = ((lq ^ ((lr >> 1) & 3)) << 3);

  const u16* Arow0 = Ab + (long long)(m0 + rowb)      * lda + kc_e + koff;
  const u16* Arow1 = Ab + (long long)(m0 + rowb + 64) * lda + kc_e + koff;
  const u16* Brow0 = Bb + (long long)(n0 + rowb)      * ldb + kc_e + koff;
  const u16* Brow1 = Bb + (long long)(n0 + rowb + 64) * ldb + kc_e + koff;

  f32x4 acc[4][4] = {};

  auto stage = [&](int kt, int b) {
    const int k0 = kt << 5;
    async16(&As[b][tid * 8],         Arow0 + k0);
    async16(&As[b][(tid + 256) * 8], Arow1 + k0);
    async16(&Bs[b][tid * 8],         Brow0 + k0);
    async16(&Bs[b][(tid + 256) * 8], Brow1 + k0);
  };

  stage(0, 0);
  if (nk > 1) stage(1, 1);
  int cur = 0;
  for (int kt = 0; kt < nk; ++kt) {
    if (kt + 2 < nk) {
      int nb = cur + 2; if (nb >= 3) nb -= 3;
      stage(kt + 2, nb);
      asm volatile("s_waitcnt vmcnt(8)" ::: "memory");
    } else if (kt + 1 < nk) {
      asm volatile("s_waitcnt vmcnt(4)" ::: "memory");
    } else {
      asm volatile("s_waitcnt vmcnt(0)" ::: "memory");
    }
    asm volatile("s_barrier" ::: "memory");   // publish tile kt to all waves

    bf16x8 af[4], bfv[4];
#pragma unroll
    for (int mi = 0; mi < 4; ++mi)
      af[mi] = __builtin_bit_cast(bf16x8, *(const s16x8*)&As[cur][((wm + mi * 16 + lr) << 5) + kslot]);
#pragma unroll
    for (int ni = 0; ni < 4; ++ni)
      bfv[ni] = __builtin_bit_cast(bf16x8, *(const s16x8*)&Bs[cur][((wn + ni * 16 + lr) << 5) + kslot]);
#pragma unroll
    for (int mi = 0; mi < 4; ++mi)
#pragma unroll
      for (int ni = 0; ni < 4; ++ni)
        acc[mi][ni] = __builtin_amdgcn_mfma_f32_16x16x32_bf16(af[mi], bfv[ni], acc[mi][ni], 0, 0, 0);

    asm volatile("s_barrier" ::: "memory");   // protect buffer cur
    ++cur; if (cur == 3) cur = 0;
  }

  if (Part) {
    float* P = Part + (long long)zb * sCb;
#pragma unroll
    for (int ni = 0; ni < 4; ++ni) {
      const int col = n0 + wn + ni * 16 + lr;
#pragma unroll
      for (int mi = 0; mi < 4; ++mi) {
        const int row0 = m0 + wm + mi * 16 + (lq << 2);
#pragma unroll
        for (int r = 0; r < 4; ++r)
          P[(long long)(row0 + r) * ldc + col] = acc[mi][ni][r];
      }
    }
    return;
  }

  const long long Co = zb * sCb + zh * sCh;
#pragma unroll
  for (int ni = 0; ni < 4; ++ni) {
    const int col = n0 + wn + ni * 16 + lr;
    const float badd = bias ? bias[col] : 0.0f;
#pragma unroll
    for (int mi = 0; mi < 4; ++mi) {
      const int row0 = m0 + wm + mi * 16 + (lq << 2);
#pragma unroll
      for (int r = 0; r < 4; ++r) {
        float v = acc[mi][ni][r] + badd;
        if (epi == 1) v = gelu_f(v);
        Cb[Co + (long long)(row0 + r) * ldc + col] = f2b(v);
      }
    }
  }
}

// sum S f32 partial planes + bias -> bf16. N pow2. 4 elems/thread.
__global__ __launch_bounds__(256) void reduce_bias(
    const float* __restrict__ Part, long long sPart, int S,
    const float* __restrict__ bias, int N,
    u16* __restrict__ Out, long long total)
{
  const long long i = ((long long)blockIdx.x * 256 + threadIdx.x) * 4;
  if (i >= total) return;
  f32x4 s = *(const f32x4*)(Part + i);
  for (int p = 1; p < S; ++p) {
    const f32x4 v = *(const f32x4*)(Part + (long long)p * sPart + i);
    s[0] += v[0]; s[1] += v[1]; s[2] += v[2]; s[3] += v[3];
  }
  const int colb = (int)(i & (N - 1));
#pragma unroll
  for (int j = 0; j < 4; ++j)
    Out[i + j] = f2b(s[j] + bias[colb + j]);
}

// sum S f32 partial planes + conv-bias + BN(eval) + ReLU -> bf16 NHWC.
__global__ __launch_bounds__(256) void reduce_bn(
    const float* __restrict__ Part, long long sPart, int S,
    const float* __restrict__ bn_g, const float* __restrict__ bn_b,
    const float* __restrict__ bn_m, const float* __restrict__ bn_v,
    const float* __restrict__ cb, int Cout,
    u16* __restrict__ Out, long long total)
{
  const long long i = ((long long)blockIdx.x * 256 + threadIdx.x) * 4;
  if (i >= total) return;
  f32x4 s = *(const f32x4*)(Part + i);
  for (int p = 1; p < S; ++p) {
    const f32x4 v = *(const f32x4*)(Part + (long long)p * sPart + i);
    s[0] += v[0]; s[1] += v[1]; s[2] += v[2]; s[3] += v[3];
  }
  const int colb = (int)(i & (Cout - 1));
#pragma unroll
  for (int j = 0; j < 4; ++j) {
    const int col = colb + j;
    const float inv = rsqrtf(bn_v[col] + 1e-5f);
    const float bs = bn_g[col] * inv;
    const float bsh = (cb[col] - bn_m[col]) * bs + bn_b[col];
    Out[i + j] = f2b(fmaxf(s[j] * bs + bsh, 0.0f));
  }
}

// ---------------------------------------------------------------------------
// Implicit-GEMM conv3x3 SAME, NHWC bf16 in, fused BN(eval)+ReLU, bf16 out.
// K = 9*Cin as ((dy*3+dx)*Cin + ci). Wr: [Npad x K] bf16. OOB -> zero page.
// Tile 128(M on blockIdx.x) x 64(N on blockIdx.y); blockIdx.z = k-slice when
// Part != nullptr (slice covers k-tiles [z*nk,(z+1)*nk), writes f32 partial;
// reduce_bn applies the epilogue). Triple-buffered counted-vmcnt pipeline
// + XOR-swizzled LDS. nk % 3 == 0 (72/72/72/36 all are).
// ---------------------------------------------------------------------------
__global__ __launch_bounds__(256) void conv_gemm(
    const u16* __restrict__ U, const u16* __restrict__ Wr,
    u16* __restrict__ Out,
    const float* __restrict__ bn_g, const float* __restrict__ bn_b,
    const float* __restrict__ bn_m, const float* __restrict__ bn_v,
    const float* __restrict__ cb,
    const u16* __restrict__ zpg,
    int H, int W, int l2w, int l2hw, int l2c, int CoutReal, int Kdim, int nk,
    float* __restrict__ Part, long long sPart)
{
  __shared__ u16 As[3][128 * 32];   // 8 KB per buffer
  __shared__ u16 Bs[3][64 * 32];    // 4 KB per buffer
  const int tid = threadIdx.x;
  const int m0 = blockIdx.x << 7, n0 = blockIdx.y << 6;   // M on x (XCD share)
  const int slice = blockIdx.z;
  const int koff = Part ? (slice * (nk << 5)) : 0;
  const int wave = tid >> 6, lane = tid & 63;
  const int wm = (wave >> 1) << 6, wn = (wave & 1) << 5;
  const int lr = lane & 15, lq = lane >> 4;
  const int rowb = tid >> 2;
  const int kc_e = (((tid & 3) ^ ((tid >> 3) & 3)) << 3);
  const int kslot = ((lq ^ ((lr >> 1) & 3)) << 3);
  const int hwmask = (1 << l2hw) - 1, wmask = (1 << l2w) - 1, cmask = (1 << l2c) - 1;

  // Per-thread A-row geometry (phase-invariant): two halves i=0,1.
  int yA[2], xA[2];
  long long baseA[2];
  {
#pragma unroll
    for (int i = 0; i < 2; ++i) {
      const int mrow = m0 + rowb + (i << 6);
      const int img = mrow >> l2hw;
      const int rem = mrow & hwmask;
      yA[i] = rem >> l2w; xA[i] = rem & wmask;
      baseA[i] = (long long)(img << l2hw);
    }
  }
  const u16* Bbase = Wr + (long long)(n0 + rowb) * Kdim + kc_e + koff;

  f32x4 acc[4][2] = {};

  // Stage k-tile kt into buffer b: exactly 3 async16 per thread (2 A + 1 B).
  auto stage = [&](int kt, int b) {
    const int k0 = kt << 5;
    const int kabs = koff + k0 + kc_e;
    const int t = kabs >> l2c, ci = kabs & cmask;
    const int dy = (t * 86) >> 8;   // t/3 for t in [0,8]
    const int dx = t - dy * 3;
#pragma unroll
    for (int i = 0; i < 2; ++i) {
      const int yy = yA[i] + dy - 1, xx = xA[i] + dx - 1;
      const u16* src = ((unsigned)yy < (unsigned)H && (unsigned)xx < (unsigned)W)
          ? U + (((baseA[i] + (yy << l2w) + xx) << l2c) + ci)
          : zpg;
      async16(&As[b][(tid + (i << 8)) * 8], src);
    }
    async16(&Bs[b][tid * 8], Bbase + k0);
  };

  // Prologue: tiles 0 and 1 in flight (6 loads/thread outstanding).
  stage(0, 0);
  stage(1, 1);

  for (int t0 = 0; t0 < nk; t0 += 3) {
#pragma unroll
    for (int p = 0; p < 3; ++p) {
      const int tt = t0 + p;
      if (tt + 2 < nk) {
        stage(tt + 2, (p + 2) % 3);
        asm volatile("s_waitcnt vmcnt(6)" ::: "memory");
      } else if (tt + 1 < nk) {
        asm volatile("s_waitcnt vmcnt(3)" ::: "memory");
      } else {
        asm volatile("s_waitcnt vmcnt(0)" ::: "memory");
      }
      asm volatile("s_barrier" ::: "memory");   // publish tile tt

      bf16x8 af[4], bfv[2];
#pragma unroll
      for (int mi = 0; mi < 4; ++mi)
        af[mi] = __builtin_bit_cast(bf16x8, *(const s16x8*)&As[p][((wm + mi * 16 + lr) << 5) + kslot]);
#pragma unroll
      for (int ni = 0; ni < 2; ++ni)
        bfv[ni] = __builtin_bit_cast(bf16x8, *(const s16x8*)&Bs[p][((wn + ni * 16 + lr) << 5) + kslot]);
#pragma unroll
      for (int mi = 0; mi < 4; ++mi)
#pragma unroll
        for (int ni = 0; ni < 2; ++ni)
          acc[mi][ni] = __builtin_amdgcn_mfma_f32_16x16x32_bf16(af[mi], bfv[ni], acc[mi][ni], 0, 0, 0);

      asm volatile("s_barrier" ::: "memory");   // protect buffer p
    }
  }

  if (Part) {
    float* P = Part + (long long)slice * sPart;
#pragma unroll
    for (int ni = 0; ni < 2; ++ni) {
      const int col = n0 + wn + ni * 16 + lr;
#pragma unroll
      for (int mi = 0; mi < 4; ++mi) {
        const int row0 = m0 + wm + mi * 16 + (lq << 2);
#pragma unroll
        for (int r = 0; r < 4; ++r)
          P[(long long)(row0 + r) * CoutReal + col] = acc[mi][ni][r];
      }
    }
    return;
  }

#pragma unroll
  for (int ni = 0; ni < 2; ++ni) {
    const int col = n0 + wn + ni * 16 + lr;
    const bool ok = col < CoutReal;
    float bs = 0.0f, bsh = 0.0f;
    if (ok) {
      const float inv = rsqrtf(bn_v[col] + 1e-5f);
      bs = bn_g[col] * inv;
      bsh = (cb[col] - bn_m[col]) * bs + bn_b[col];
    }
#pragma unroll
    for (int mi = 0; mi < 4; ++mi) {
      const int row0 = m0 + wm + mi * 16 + (lq << 2);
#pragma unroll
      for (int r = 0; r < 4; ++r) {
        if (ok) {
          const float v = fmaxf(acc[mi][ni][r] * bs + bsh, 0.0f);
          Out[(long long)(row0 + r) * CoutReal + col] = f2b(v);
        }
      }
    }
  }
}

// --------------------------- auxiliary kernels -----------------------------

// patches f32 [64][3][128][128] -> A_pe bf16 [4096 tok][768] (k=c*256+ky*16+kx)
__global__ void pe_gather(const float* __restrict__ patches, u16* __restrict__ Ape) {
  const int t = blockIdx.x, tid = threadIdx.x;
  const int img = t >> 6, pos = t & 63, ty = pos >> 3, tx = pos & 7;
  const float* base = patches + (long long)img * 3 * 128 * 128;
  u16* dst = Ape + (long long)t * 768;
  for (int k = tid; k < 768; k += 256) {
    const int c = k >> 8, rr = k & 255, ky = rr >> 4, kx = rr & 15;
    dst[k] = f2b(base[c * 16384 + (ty * 16 + ky) * 128 + tx * 16 + kx]);
  }
}

// V slice of qkv -> Vt [z=bq*8+h][128 d][512 t] bf16 (LDS transpose)
__global__ void vt_transpose(const u16* __restrict__ qkv, u16* __restrict__ Vt) {
  __shared__ u16 lds[64 * 130];
  const int tt = blockIdx.x;       // t-tile 0..7
  const int z = blockIdx.y;        // 0..63
  const int bq = z >> 3, h = z & 7;
  const int tid = threadIdx.x;
  for (int idx = tid; idx < 64 * 128; idx += 256) {
    const int t = idx >> 7, d = idx & 127;
    lds[t * 130 + d] = qkv[(long long)(bq * 512 + tt * 64 + t) * 3072 + 2048 + h * 128 + d];
  }
  __syncthreads();
  for (int idx = tid; idx < 64 * 128; idx += 256) {
    const int d = idx >> 6, t = idx & 63;
    Vt[(long long)z * 65536 + d * 512 + tt * 64 + t] = lds[t * 130 + d];
  }
}

// in-place row softmax with 1/sqrt(128) scale on bf16 rows of 512
__global__ __launch_bounds__(256) void softmax_rows(u16* __restrict__ P) {
  __shared__ float red[8];
  const long long base = (long long)blockIdx.x * 512;
  const int tid = threadIdx.x;
  const float sc = 0.08838834764831845f;
  float x0 = b2f(P[base + tid]) * sc;
  float x1 = b2f(P[base + tid + 256]) * sc;
  float mx = fmaxf(x0, x1);
  for (int o = 32; o; o >>= 1) mx = fmaxf(mx, __shfl_down(mx, o));
  if ((tid & 63) == 0) red[tid >> 6] = mx;
  __syncthreads();
  mx = fmaxf(fmaxf(red[0], red[1]), fmaxf(red[2], red[3]));
  const float e0 = expf(x0 - mx), e1 = expf(x1 - mx);
  float s = e0 + e1;
  for (int o = 32; o; o >>= 1) s += __shfl_down(s, o);
  __syncthreads();
  if ((tid & 63) == 0) red[tid >> 6] = s;
  __syncthreads();
  s = red[0] + red[1] + red[2] + red[3];
  const float inv = 1.0f / s;
  P[base + tid] = f2b(e0 * inv);
  P[base + tid + 256] = f2b(e1 * inv);
}

// hs_b = LN(hs_b + P; g,b).  P bf16.  One block per row of 1024.
__global__ __launch_bounds__(256) void ln_kernel(
    u16* __restrict__ hsb, const u16* __restrict__ P,
    const float* __restrict__ gw, const float* __restrict__ bw)
{
  __shared__ float red[8];
  const int r = blockIdx.x, tid = threadIdx.x;
  float x[4], s = 0.0f, s2 = 0.0f;
#pragma unroll
  for (int i = 0; i < 4; ++i) {
    const int c = tid + i * 256;
    const float v = b2f(hsb[(long long)r * 1024 + c]) + b2f(P[(long long)r * 1024 + c]);
    x[i] = v; s += v; s2 += v * v;
  }
  for (int o = 32; o; o >>= 1) { s += __shfl_down(s, o); s2 += __shfl_down(s2, o); }
  if ((tid & 63) == 0) { red[tid >> 6] = s; red[4 + (tid >> 6)] = s2; }
  __syncthreads();
  s  = red[0] + red[1] + red[2] + red[3];
  s2 = red[4] + red[5] + red[6] + red[7];
  const float mean = s * (1.0f / 1024.0f);
  const float var = s2 * (1.0f / 1024.0f) - mean * mean;
  const float inv = rsqrtf(var + 1e-5f);
#pragma unroll
  for (int i = 0; i < 4; ++i) {
    const int c = tid + i * 256;
    const float y = (x[i] - mean) * inv * gw[c] + bw[c];
    hsb[(long long)r * 1024 + c] = f2b(y);
  }
}

// repack conv weights f32 [Cout][Cin][3][3] -> bf16 [Npad][9*Cin]
__global__ void repack_w(const float* __restrict__ src, u16* __restrict__ dst, int Cout, int l2c) {
  const int co = blockIdx.x, tid = threadIdx.x;
  const int Cin = 1 << l2c, K9 = 9 << l2c;
  for (int j = tid; j < K9; j += 256) {
    const int t = j >> l2c, ci = j & (Cin - 1);
    u16 v = 0;
    if (co < Cout) v = f2b(src[(long long)(co * Cin + ci) * 9 + t]);
    dst[(long long)co * K9 + j] = v;
  }
}

// bilinear x2 (half-pixel), bf16 NHWC -> bf16 NHWC (2H x 2W)
__global__ void ups2x(const u16* __restrict__ in, u16* __restrict__ out,
                      int l2h, int l2w, int l2c, long long total)
{
  const long long idx = (long long)blockIdx.x * 256 + threadIdx.x;
  if (idx >= total) return;
  const int H = 1 << l2h, W = 1 << l2w, C = 1 << l2c;
  const int c = (int)(idx & (C - 1));
  long long t = idx >> l2c;
  const int ox = (int)(t & (2 * W - 1)); t >>= (l2w + 1);
  const int oy = (int)(t & (2 * H - 1)); t >>= (l2h + 1);
  const int img = (int)t;
  const int iy = oy >> 1, ix = ox >> 1;
  int y0, y1, x0, x1; float wy0, wy1, wx0, wx1;
  if (oy & 1) { y0 = iy; y1 = min(iy + 1, H - 1); wy0 = 0.75f; wy1 = 0.25f; }
  else        { y0 = max(iy - 1, 0); y1 = iy;     wy0 = 0.25f; wy1 = 0.75f; }
  if (ox & 1) { x0 = ix; x1 = min(ix + 1, W - 1); wx0 = 0.75f; wx1 = 0.25f; }
  else        { x0 = max(ix - 1, 0); x1 = ix;     wx0 = 0.25f; wx1 = 0.75f; }
  const u16* base = in + (((long long)img) << (l2h + l2w + l2c));
  const float v00 = b2f(base[((((long long)y0 << l2w) + x0) << l2c) + c]);
  const float v01 = b2f(base[((((long long)y0 << l2w) + x1) << l2c) + c]);
  const float v10 = b2f(base[((((long long)y1 << l2w) + x0) << l2c) + c]);
  const float v11 = b2f(base[((((long long)y1 << l2w) + x1) << l2c) + c]);
  out[idx] = f2b(wy0 * (wx0 * v00 + wx1 * v01) + wy1 * (wx0 * v10 + wx1 * v11));
}

// 1x1 conv over 64 channels: C4 bf16 [262144][64] -> Z f32 [262144]
__global__ __launch_bounds__(256) void conv1x1_final(
    const u16* __restrict__ C4, const float* __restrict__ w5,
    const float* __restrict__ b5, float* __restrict__ Z)
{
  const int tid = threadIdx.x;
  const int px = blockIdx.x * 4 + (tid >> 6);
  const int lane = tid & 63;
  float v = b2f(C4[(long long)px * 64 + lane]) * w5[lane];
  for (int o = 32; o; o >>= 1) v += __shfl_down(v, o);
  if (lane == 0) Z[px] = v + b5[0];
}

// bilinear x2: Z f32 [64][64][64] -> out FLOAT32 [64][128][128]
__global__ void ups_final(const float* __restrict__ Z, float* __restrict__ out) {
  const int idx = blockIdx.x * 256 + threadIdx.x;
  const int ox = idx & 127, oy = (idx >> 7) & 127, img = idx >> 14;
  const int iy = oy >> 1, ix = ox >> 1;
  int y0, y1, x0, x1; float wy0, wy1, wx0, wx1;
  if (oy & 1) { y0 = iy; y1 = min(iy + 1, 63); wy0 = 0.75f; wy1 = 0.25f; }
  else        { y0 = max(iy - 1, 0); y1 = iy;  wy0 = 0.25f; wy1 = 0.75f; }
  if (ox & 1) { x0 = ix; x1 = min(ix + 1, 63); wx0 = 0.75f; wx1 = 0.25f; }
  else        { x0 = max(ix - 1, 0); x1 = ix;  wx0 = 0.25f; wx1 = 0.75f; }
  const float* zi = Z + (long long)img * 4096;
  const float v = wy0 * (wx0 * zi[y0 * 64 + x0] + wx1 * zi[y0 * 64 + x1]) +
                  wy1 * (wx0 * zi[y1 * 64 + x0] + wx1 * zi[y1 * 64 + x1]);
  out[idx] = v;
}

// ---------------------------------------------------------------------------
extern "C" void kernel_launch(void* const* d_in, const int* in_sizes, int n_in,
                              void* d_out, int out_size, void* d_ws, size_t ws_size,
                              hipStream_t stream)
{
  (void)in_sizes; (void)n_in; (void)out_size;
  if (ws_size < 110395648u) return;   // diagnostic: zero output => ws too small
  const float* patches = (const float*)d_in[0];
  const float* pe_w = (const float*)d_in[1];
  const float* pe_b = (const float*)d_in[2];
  const float* qkv_w = (const float*)d_in[3];
  const float* qkv_b = (const float*)d_in[4];
  const float* out_w = (const float*)d_in[5];
  const float* out_b = (const float*)d_in[6];
  const float* ln1_g = (const float*)d_in[7];
  const float* ln1_b = (const float*)d_in[8];
  const float* ff1_w = (const float*)d_in[9];
  const float* ff1_b = (const float*)d_in[10];
  const float* ff2_w = (const float*)d_in[11];
  const float* ff2_b = (const float*)d_in[12];
  const float* ln2_g = (const float*)d_in[13];
  const float* ln2_b = (const float*)d_in[14];
  const float* dwv[4] = {(const float*)d_in[15], (const float*)d_in[21], (const float*)d_in[27], (const float*)d_in[33]};
  const float* dbv[4] = {(const float*)d_in[16], (const float*)d_in[22], (const float*)d_in[28], (const float*)d_in[34]};
  const float* gv[4]  = {(const float*)d_in[17], (const float*)d_in[23], (const float*)d_in[29], (const float*)d_in[35]};
  const float* bev[4] = {(const float*)d_in[18], (const float*)d_in[24], (const float*)d_in[30], (const float*)d_in[36]};
  const float* mv[4]  = {(const float*)d_in[19], (const float*)d_in[25], (const float*)d_in[31], (const float*)d_in[37]};
  const float* vv[4]  = {(const float*)d_in[20], (const float*)d_in[26], (const float*)d_in[32], (const float*)d_in[38]};
  const float* dw5 = (const float*)d_in[39];
  const float* db5 = (const float*)d_in[40];
  float* outp = (float*)d_out;     // reference output dtype = float32
  char* ws = (char*)d_ws;

  // ---- workspace layout (peak 110,395,648 B) ------------------------------
  // transformer phase
  u16* HS_B = (u16*)(ws + 0);              // [4096][1024]
  u16* APE  = (u16*)(ws + 8388608);        // [4096][768] (dead before QKV)
  u16* QKV  = (u16*)(ws + 8388608);        // [4096][3072]   ends 33,554,432
  u16* VT   = (u16*)(ws + 33554432);       // [64][128][512] ends 41,943,040
  u16* SF   = (u16*)(ws + 41943040);       // [64][512][512] ends 75,497,472
  u16* FF1G = (u16*)(ws + 41943040);       // [4096][4096] (over dead SF)
  u16* ATT  = (u16*)(ws + 75497472);       // [4096][1024]   ends 83,886,080
  u16* P_B  = (u16*)(ws + 83886080);       // [4096][1024]   ends 92,274,688
  u16* W1   = (u16*)(ws + 92274688);       // 8.39M slot     ends 100,663,296
  u16* W2   = (u16*)(ws + 100663296);      // 8.39M slot     ends 109,051,904
  float* PART_G  = (float*)(ws + 8388608);  // [2][4096][1024] f32 over dead QKV/VT (proj & FF2, post-PV)
  float* PART_PE = (float*)(ws + 41943040); // [2][4096][1024] f32 over SF region (patch-embed phase only)
  // decoder phase (R3-VERIFIED layout; all transformer buffers except HS_B dead)
  u16* WR1 = (u16*)(ws + 8388608);         // [512][9216]    ends 17,825,792
  u16* WR2 = (u16*)(ws + 17825792);        // [256][4608]    ends 20,185,088
  u16* WR3 = (u16*)(ws + 20185088);        // [128][2304]    ends 20,774,912
  u16* C1  = (u16*)(ws + 20774912);        // [4096][512]    ends 24,969,216
  u16* U1  = (u16*)(ws + 24969216);        // [64][16][16][512] ends 41,746,432
  u16* C2  = (u16*)(ws + 41746432);        // [16384][256]   ends 50,135,040
  u16* U2  = (u16*)(ws + 50135040);        // [64][32][32][256] ends 83,689,472
  u16* C3  = (u16*)(ws + 83689472);        // [65536][128]   ends 100,466,688
  u16* U3  = (u16*)(ws + 8388608);         // [64][64][64][128] = 64MB, ends 75,497,472 (over dead WR1-3/C1/U1/C2 + lower U2)
  u16* C4  = (u16*)(ws + 75497472);        // [262144][64]   ends 109,051,904 (over dead upper-U2/C3/W-slots)
  float* PARTC1 = (float*)(ws + 41746432); // conv1 partials [4][4096][512] f32, ends 75,300,864 (C2/U2 region, unwritten at conv1 time)
  float* PARTC2 = (float*)(ws + 50331648); // conv2 partials [2][16384][256] f32, ends 83,886,080 (disjoint from U1 input & C2 output; C3 written later)
  u16* ZPG = (u16*)(ws + 109051904);       // 256 B zero page (live through all convs)
  u16* WR4 = (u16*)(ws + 109052160);       // [128][1152]    ends 109,347,072
  float* Z = (float*)(ws + 109347072);     // [262144] f32   ends 110,395,648

  // ---- patch embedding (split-K S=2) --------------------------------------
  pe_gather<<<4096, 256, 0, stream>>>(patches, APE);
  cvt_f2b<<<768, 256, 0, stream>>>(pe_w, W1, 786432);
  gemm_bt<<<dim3(8, 32, 2), 256, 0, stream>>>(
      APE, 768, 0, 0, W1, 768, 0, 0,
      HS_B, 1024, 4194304, 0, nullptr, 0, 1, 12, PART_PE);
  reduce_bias<<<4096, 256, 0, stream>>>(PART_PE, 4194304, 2, pe_b, 1024, HS_B, 4194304LL);

  // ---- transformer --------------------------------------------------------
  for (int l = 0; l < 2; ++l) {
    cvt_f2b<<<3072, 256, 0, stream>>>(qkv_w + (long long)l * 3145728, W1, 3145728);
    gemm_bt<<<dim3(24, 32, 1), 256, 0, stream>>>(
        HS_B, 1024, 0, 0, W1, 1024, 0, 0,
        QKV, 3072, 0, 0, qkv_b + l * 3072, 0, 1, 32, nullptr);
    vt_transpose<<<dim3(8, 64), 256, 0, stream>>>(QKV, VT);
    // S = Q K^T for all 64 (batch,head)
    gemm_bt<<<dim3(4, 4, 64), 256, 0, stream>>>(
        QKV, 3072, 1572864, 128, QKV + 1024, 3072, 1572864, 128,
        SF, 512, 2097152, 262144, nullptr, 0, 8, 4, nullptr);
    softmax_rows<<<32768, 256, 0, stream>>>(SF);
    // O = P V
    gemm_bt<<<dim3(1, 4, 64), 256, 0, stream>>>(
        SF, 512, 2097152, 262144, VT, 512, 524288, 65536,
        ATT, 1024, 524288, 128, nullptr, 0, 8, 16, nullptr);
    // proj (split-K S=2; QKV/VT dead now -> PART_G safe)
    cvt_f2b<<<1024, 256, 0, stream>>>(out_w + (long long)l * 1048576, W2, 1048576);
    gemm_bt<<<dim3(8, 32, 2), 256, 0, stream>>>(
        ATT, 1024, 0, 0, W2, 1024, 0, 0,
        P_B, 1024, 4194304, 0, nullptr, 0, 1, 16, PART_G);
    reduce_bias<<<4096, 256, 0, stream>>>(PART_G, 4194304, 2, out_b + l * 1024, 1024, P_B, 4194304LL);
    ln_kernel<<<4096, 256, 0, stream>>>(HS_B, P_B, ln1_g + l * 1024, ln1_b + l * 1024);
    cvt_f2b<<<4096, 256, 0, stream>>>(ff1_w + (long long)l * 4194304, W1, 4194304);
    cvt_f2b<<<4096, 256, 0, stream>>>(ff2_w + (long long)l * 4194304, W2, 4194304);
    gemm_bt<<<dim3(32, 32, 1), 256, 0, stream>>>(
        HS_B, 1024, 0, 0, W1, 1024, 0, 0,
        FF1G, 4096, 0, 0, ff1_b + l * 4096, 1, 1, 32, nullptr);
    // FF2 (split-K S=2, nk=64)
    gemm_bt<<<dim3(8, 32, 2), 256, 0, stream>>>(
        FF1G, 4096, 0, 0, W2, 4096, 0, 0,
        P_B, 1024, 4194304, 0, nullptr, 0, 1, 64, PART_G);
    reduce_bias<<<4096, 256, 0, stream>>>(PART_G, 4194304, 2, ff2_b + l * 1024, 1024, P_B, 4194304LL);
    ln_kernel<<<4096, 256, 0, stream>>>(HS_B, P_B, ln2_g + l * 1024, ln2_b + l * 1024);
  }

  // ---- CNN decoder --------------------------------------------------------
  hipMemsetAsync((void*)ZPG, 0, 256, stream);
  repack_w<<<512, 256, 0, stream>>>(dwv[0], WR1, 512, 10);
  repack_w<<<256, 256, 0, stream>>>(dwv[1], WR2, 256, 9);
  repack_w<<<128, 256, 0, stream>>>(dwv[2], WR3, 128, 8);
  repack_w<<<128, 256, 0, stream>>>(dwv[3], WR4, 64, 7);

  // conv1: split-K S=4 (1024 blocks, 4/CU), partial [4][4096][512] f32
  conv_gemm<<<dim3(32, 8, 4), 256, 0, stream>>>(
      HS_B, WR1, C1, gv[0], bev[0], mv[0], vv[0], dbv[0], ZPG,
      8, 8, 3, 6, 10, 512, 9216, 72, PARTC1, 2097152);
  reduce_bn<<<2048, 256, 0, stream>>>(PARTC1, 2097152, 4,
      gv[0], bev[0], mv[0], vv[0], dbv[0], 512, C1, 2097152LL);
  ups2x<<<32768, 256, 0, stream>>>(C1, U1, 3, 3, 9, 8388608LL);
  // conv2: split-K S=2 (1024 blocks), partial [2][16384][256] f32
  conv_gemm<<<dim3(128, 4, 2), 256, 0, stream>>>(
      U1, WR2, C2, gv[1], bev[1], mv[1], vv[1], dbv[1], ZPG,
      16, 16, 4, 8, 9, 256, 4608, 72, PARTC2, 4194304);
  reduce_bn<<<4096, 256, 0, stream>>>(PARTC2, 4194304, 2,
      gv[1], bev[1], mv[1], vv[1], dbv[1], 256, C2, 4194304LL);
  ups2x<<<65536, 256, 0, stream>>>(C2, U2, 4, 4, 8, 16777216LL);
  conv_gemm<<<dim3(512, 2, 1), 256, 0, stream>>>(
      U2, WR3, C3, gv[2], bev[2], mv[2], vv[2], dbv[2], ZPG,
      32, 32, 5, 10, 8, 128, 2304, 72, nullptr, 0);
  ups2x<<<131072, 256, 0, stream>>>(C3, U3, 5, 5, 7, 33554432LL);
  conv_gemm<<<dim3(2048, 1, 1), 256, 0, stream>>>(
      U3, WR4, C4, gv[3], bev[3], mv[3], vv[3], dbv[3], ZPG,
      64, 64, 6, 12, 7, 64, 1152, 36, nullptr, 0);
  conv1x1_final<<<65536, 256, 0, stream>>>(C4, dw5, db5, Z);
  ups_final<<<4096, 256, 0, stream>>>(Z, outp);
}

// Round 6
// 1272.564 us; speedup vs baseline: 1.1814x; 1.0261x over previous
//
#include <hip/hip_runtime.h>
#include <stdint.h>

// ---------------------------------------------------------------------------
// LocalDino forward on MI355X (gfx950).
// Inputs: float32. OUTPUT: float32 (reference dtype). Internal: bf16 + f32 acc.
// Heavy math via mfma_f32_16x16x32_bf16. gemm_bt and conv_gemm use:
//   - triple-buffered counted-vmcnt software pipeline
//   - conflict-free XOR-swizzled LDS (R2 verified conflicts -> 0)
//   - SPLIT-K (R3: latency-bound at 1 block/CU; fix = more blocks/CU)
//   - conv K-tile iteration PERMUTED ci-chunk-outer/tap-inner (R5: 274 MB
//     HBM fetch on conv3 = 9-tap im2col re-fetch; tap-adjacent phases put
//     reuse distance inside the 4 MB per-XCD L2). kt = (g%9)*CC + g/9.
// Decoder workspace layout is the R3-verified one; partials in audited
// dead regions. conv grid keeps M on blockIdx.x (XCD A-panel sharing).
// ---------------------------------------------------------------------------

typedef unsigned short u16;
typedef __bf16 bf16x8 __attribute__((ext_vector_type(8)));
typedef short  s16x8  __attribute__((ext_vector_type(8)));
typedef float  f32x4  __attribute__((ext_vector_type(4)));

__device__ __forceinline__ float b2f(u16 x) { return __uint_as_float(((unsigned)x) << 16); }
__device__ __forceinline__ u16 f2b(float f) {
  unsigned u = __float_as_uint(f);
  unsigned r = (u + 0x7fffu + ((u >> 16) & 1u)) >> 16;   // RNE
  return (u16)r;
}
__device__ __forceinline__ void async16(u16* lds, const u16* g) {
  __builtin_amdgcn_global_load_lds((const __attribute__((address_space(1))) void*)g,
                                   (__attribute__((address_space(3))) void*)lds, 16, 0, 0);
}
__device__ __forceinline__ float gelu_f(float x) {
  return 0.5f * x * (1.0f + erff(x * 0.70710678118654752f));  // exact gelu
}

// f32 -> bf16 canonicalization
__global__ __launch_bounds__(256) void cvt_f2b(const float* __restrict__ src,
                                               u16* __restrict__ dst, int n) {
  const int i = (blockIdx.x * 256 + threadIdx.x) * 4;
  if (i + 3 < n) {
    const float4 v = *(const float4*)(src + i);
    dst[i] = f2b(v.x); dst[i + 1] = f2b(v.y); dst[i + 2] = f2b(v.z); dst[i + 3] = f2b(v.w);
  }
}

// ---------------------------------------------------------------------------
// bf16 GEMM: C[m,n] = sum_k A[m,k]*B[n,k] (+bias[n]) (+gelu). Cb bf16 output.
// Batched via blockIdx.z: off = (z/ZH)*s?b + (z%ZH)*s?h.
// SPLIT-K mode: Part != nullptr -> blockIdx.z = k-slice (ZH must be 1);
// slice covers k-tiles [z*nk, (z+1)*nk); writes f32 partial at
// Part + z*sCb + row*ldc + col (bias/epilogue applied by reduce_bias).
// ---------------------------------------------------------------------------
__global__ __launch_bounds__(256) void gemm_bt(
    const u16* __restrict__ A, int lda, long long sAb, long long sAh,
    const u16* __restrict__ B, int ldb, long long sBb, long long sBh,
    u16* __restrict__ Cb, int ldc, long long sCb, long long sCh,
    const float* __restrict__ bias, int epi, int ZH, int nk,
    float* __restrict__ Part)
{
  __shared__ u16 As[3][128 * 32];
  __shared__ u16 Bs[3][128 * 32];
  const int tid = threadIdx.x;
  const int zb = blockIdx.z / ZH, zh = blockIdx.z % ZH;
  const u16* Ab = A + zb * sAb + zh * sAh;
  const u16* Bb = B + zb * sBb + zh * sBh;
  const int m0 = blockIdx.y << 7, n0 = blockIdx.x << 7;
  const int wave = tid >> 6, lane = tid & 63;
  const int wm = (wave >> 1) << 6, wn = (wave & 1) << 6;
  const int lr = lane & 15, lq = lane >> 4;
  const int rowb = tid >> 2;
  const int koff = Part ? (zb * (nk << 5)) : 0;   // k-slice element offset
  // swizzled k-chunk this thread stages (rows rowb and rowb+64 share
  // (row>>1)&3):
  const int kc_e = (((tid & 3) ^ ((tid >> 3) & 3)) << 3);
  // swizzled LDS element offset for fragment reads:
  const int kslot = ((lq ^ ((lr >> 1) & 3)) << 3);

  const u16* Arow0 = Ab + (long long)(m0 + rowb)      * lda + kc_e + koff;
  const u16* Arow1 = Ab + (long long)(m0 + rowb + 64) * lda + kc_e + koff;
  const u16* Brow0 = Bb + (long long)(n0 + rowb)      * ldb + kc_e + koff;
  const u16* Brow1 = Bb + (long long)(n0 + rowb + 64) * ldb + kc_e + koff;

  f32x4 acc[4][4] = {};

  auto stage = [&](int kt, int b) {
    const int k0 = kt << 5;
    async16(&As[b][tid * 8],         Arow0 + k0);
    async16(&As[b][(tid + 256) * 8], Arow1 + k0);
    async16(&Bs[b][tid * 8],         Brow0 + k0);
    async16(&Bs[b][(tid + 256) * 8], Brow1 + k0);
  };

  stage(0, 0);
  if (nk > 1) stage(1, 1);
  int cur = 0;
  for (int kt = 0; kt < nk; ++kt) {
    if (kt + 2 < nk) {
      int nb = cur + 2; if (nb >= 3) nb -= 3;
      stage(kt + 2, nb);
      asm volatile("s_waitcnt vmcnt(8)" ::: "memory");
    } else if (kt + 1 < nk) {
      asm volatile("s_waitcnt vmcnt(4)" ::: "memory");
    } else {
      asm volatile("s_waitcnt vmcnt(0)" ::: "memory");
    }
    asm volatile("s_barrier" ::: "memory");   // publish tile kt to all waves

    bf16x8 af[4], bfv[4];
#pragma unroll
    for (int mi = 0; mi < 4; ++mi)
      af[mi] = __builtin_bit_cast(bf16x8, *(const s16x8*)&As[cur][((wm + mi * 16 + lr) << 5) + kslot]);
#pragma unroll
    for (int ni = 0; ni < 4; ++ni)
      bfv[ni] = __builtin_bit_cast(bf16x8, *(const s16x8*)&Bs[cur][((wn + ni * 16 + lr) << 5) + kslot]);
#pragma unroll
    for (int mi = 0; mi < 4; ++mi)
#pragma unroll
      for (int ni = 0; ni < 4; ++ni)
        acc[mi][ni] = __builtin_amdgcn_mfma_f32_16x16x32_bf16(af[mi], bfv[ni], acc[mi][ni], 0, 0, 0);

    asm volatile("s_barrier" ::: "memory");   // protect buffer cur
    ++cur; if (cur == 3) cur = 0;
  }

  if (Part) {
    float* P = Part + (long long)zb * sCb;
#pragma unroll
    for (int ni = 0; ni < 4; ++ni) {
      const int col = n0 + wn + ni * 16 + lr;
#pragma unroll
      for (int mi = 0; mi < 4; ++mi) {
        const int row0 = m0 + wm + mi * 16 + (lq << 2);
#pragma unroll
        for (int r = 0; r < 4; ++r)
          P[(long long)(row0 + r) * ldc + col] = acc[mi][ni][r];
      }
    }
    return;
  }

  const long long Co = zb * sCb + zh * sCh;
#pragma unroll
  for (int ni = 0; ni < 4; ++ni) {
    const int col = n0 + wn + ni * 16 + lr;
    const float badd = bias ? bias[col] : 0.0f;
#pragma unroll
    for (int mi = 0; mi < 4; ++mi) {
      const int row0 = m0 + wm + mi * 16 + (lq << 2);
#pragma unroll
      for (int r = 0; r < 4; ++r) {
        float v = acc[mi][ni][r] + badd;
        if (epi == 1) v = gelu_f(v);
        Cb[Co + (long long)(row0 + r) * ldc + col] = f2b(v);
      }
    }
  }
}

// sum S f32 partial planes + bias -> bf16. N pow2. 4 elems/thread.
__global__ __launch_bounds__(256) void reduce_bias(
    const float* __restrict__ Part, long long sPart, int S,
    const float* __restrict__ bias, int N,
    u16* __restrict__ Out, long long total)
{
  const long long i = ((long long)blockIdx.x * 256 + threadIdx.x) * 4;
  if (i >= total) return;
  f32x4 s = *(const f32x4*)(Part + i);
  for (int p = 1; p < S; ++p) {
    const f32x4 v = *(const f32x4*)(Part + (long long)p * sPart + i);
    s[0] += v[0]; s[1] += v[1]; s[2] += v[2]; s[3] += v[3];
  }
  const int colb = (int)(i & (N - 1));
#pragma unroll
  for (int j = 0; j < 4; ++j)
    Out[i + j] = f2b(s[j] + bias[colb + j]);
}

// sum S f32 partial planes + conv-bias + BN(eval) + ReLU -> bf16 NHWC.
__global__ __launch_bounds__(256) void reduce_bn(
    const float* __restrict__ Part, long long sPart, int S,
    const float* __restrict__ bn_g, const float* __restrict__ bn_b,
    const float* __restrict__ bn_m, const float* __restrict__ bn_v,
    const float* __restrict__ cb, int Cout,
    u16* __restrict__ Out, long long total)
{
  const long long i = ((long long)blockIdx.x * 256 + threadIdx.x) * 4;
  if (i >= total) return;
  f32x4 s = *(const f32x4*)(Part + i);
  for (int p = 1; p < S; ++p) {
    const f32x4 v = *(const f32x4*)(Part + (long long)p * sPart + i);
    s[0] += v[0]; s[1] += v[1]; s[2] += v[2]; s[3] += v[3];
  }
  const int colb = (int)(i & (Cout - 1));
#pragma unroll
  for (int j = 0; j < 4; ++j) {
    const int col = colb + j;
    const float inv = rsqrtf(bn_v[col] + 1e-5f);
    const float bs = bn_g[col] * inv;
    const float bsh = (cb[col] - bn_m[col]) * bs + bn_b[col];
    Out[i + j] = f2b(fmaxf(s[j] * bs + bsh, 0.0f));
  }
}

// ---------------------------------------------------------------------------
// Implicit-GEMM conv3x3 SAME, NHWC bf16 in, fused BN(eval)+ReLU, bf16 out.
// K = 9*Cin as ((dy*3+dx)*Cin + ci). Wr: [Npad x K] bf16. OOB -> zero page.
// Tile 128(M on blockIdx.x) x 64(N on blockIdx.y); blockIdx.z = k-slice when
// Part != nullptr. K-tile ITERATION is permuted ci-chunk-outer / tap-inner:
// phase g (global over all slices) -> kt = (g%9)*CC + g/9, CC = Kdim/288.
// Nine consecutive phases re-read the same ~12 KB input window -> tap reuse
// hits per-XCD L2 (R5: linear order fetched 274 MB for a 33.5 MB input).
// Slice z covers ci-chunks [z*nk/9, (z+1)*nk/9) x all 9 taps (exact
// partition of K). Triple-buffered counted-vmcnt pipeline + XOR-swizzled
// LDS. nk % 9 == 0 (72/72/72/36 all are).
// ---------------------------------------------------------------------------
__global__ __launch_bounds__(256) void conv_gemm(
    const u16* __restrict__ U, const u16* __restrict__ Wr,
    u16* __restrict__ Out,
    const float* __restrict__ bn_g, const float* __restrict__ bn_b,
    const float* __restrict__ bn_m, const float* __restrict__ bn_v,
    const float* __restrict__ cb,
    const u16* __restrict__ zpg,
    int H, int W, int l2w, int l2hw, int l2c, int CoutReal, int Kdim, int nk,
    float* __restrict__ Part, long long sPart)
{
  __shared__ u16 As[3][128 * 32];   // 8 KB per buffer
  __shared__ u16 Bs[3][64 * 32];    // 4 KB per buffer
  const int tid = threadIdx.x;
  const int m0 = blockIdx.x << 7, n0 = blockIdx.y << 6;   // M on x (XCD share)
  const int slice = blockIdx.z;
  const int base = slice * nk;            // global phase base for this slice
  const int CC = Kdim / 288;              // total K-tiles / 9 = Cin/32
  const int wave = tid >> 6, lane = tid & 63;
  const int wm = (wave >> 1) << 6, wn = (wave & 1) << 5;
  const int lr = lane & 15, lq = lane >> 4;
  const int rowb = tid >> 2;
  const int kc_e = (((tid & 3) ^ ((tid >> 3) & 3)) << 3);
  const int kslot = ((lq ^ ((lr >> 1) & 3)) << 3);
  const int hwmask = (1 << l2hw) - 1, wmask = (1 << l2w) - 1, cmask = (1 << l2c) - 1;

  // Per-thread A-row geometry (phase-invariant): two halves i=0,1.
  int yA[2], xA[2];
  long long baseA[2];
  {
#pragma unroll
    for (int i = 0; i < 2; ++i) {
      const int mrow = m0 + rowb + (i << 6);
      const int img = mrow >> l2hw;
      const int rem = mrow & hwmask;
      yA[i] = rem >> l2w; xA[i] = rem & wmask;
      baseA[i] = (long long)(img << l2hw);
    }
  }
  const u16* Bbase = Wr + (long long)(n0 + rowb) * Kdim + kc_e;

  f32x4 acc[4][2] = {};

  // Stage phase ph (0..nk-1 within slice) into buffer b: 3 async16/thread.
  auto stage = [&](int ph, int b) {
    const int g = base + ph;
    const int gd = g / 9;                 // ci-chunk index
    const int tap = g - gd * 9;           // tap index 0..8
    const int kt = tap * CC + gd;         // absolute K-tile (tap-major layout)
    const int kabs = (kt << 5) + kc_e;
    const int t = kabs >> l2c, ci = kabs & cmask;
    const int dy = (t * 86) >> 8;   // t/3 for t in [0,8]
    const int dx = t - dy * 3;
#pragma unroll
    for (int i = 0; i < 2; ++i) {
      const int yy = yA[i] + dy - 1, xx = xA[i] + dx - 1;
      const u16* src = ((unsigned)yy < (unsigned)H && (unsigned)xx < (unsigned)W)
          ? U + (((baseA[i] + (yy << l2w) + xx) << l2c) + ci)
          : zpg;
      async16(&As[b][(tid + (i << 8)) * 8], src);
    }
    async16(&Bs[b][tid * 8], Bbase + (kt << 5));
  };

  // Prologue: phases 0 and 1 in flight (6 loads/thread outstanding).
  stage(0, 0);
  stage(1, 1);

  for (int t0 = 0; t0 < nk; t0 += 3) {
#pragma unroll
    for (int p = 0; p < 3; ++p) {
      const int tt = t0 + p;
      if (tt + 2 < nk) {
        stage(tt + 2, (p + 2) % 3);
        asm volatile("s_waitcnt vmcnt(6)" ::: "memory");
      } else if (tt + 1 < nk) {
        asm volatile("s_waitcnt vmcnt(3)" ::: "memory");
      } else {
        asm volatile("s_waitcnt vmcnt(0)" ::: "memory");
      }
      asm volatile("s_barrier" ::: "memory");   // publish phase tt

      bf16x8 af[4], bfv[2];
#pragma unroll
      for (int mi = 0; mi < 4; ++mi)
        af[mi] = __builtin_bit_cast(bf16x8, *(const s16x8*)&As[p][((wm + mi * 16 + lr) << 5) + kslot]);
#pragma unroll
      for (int ni = 0; ni < 2; ++ni)
        bfv[ni] = __builtin_bit_cast(bf16x8, *(const s16x8*)&Bs[p][((wn + ni * 16 + lr) << 5) + kslot]);
#pragma unroll
      for (int mi = 0; mi < 4; ++mi)
#pragma unroll
        for (int ni = 0; ni < 2; ++ni)
          acc[mi][ni] = __builtin_amdgcn_mfma_f32_16x16x32_bf16(af[mi], bfv[ni], acc[mi][ni], 0, 0, 0);

      asm volatile("s_barrier" ::: "memory");   // protect buffer p
    }
  }

  if (Part) {
    float* P = Part + (long long)slice * sPart;
#pragma unroll
    for (int ni = 0; ni < 2; ++ni) {
      const int col = n0 + wn + ni * 16 + lr;
#pragma unroll
      for (int mi = 0; mi < 4; ++mi) {
        const int row0 = m0 + wm + mi * 16 + (lq << 2);
#pragma unroll
        for (int r = 0; r < 4; ++r)
          P[(long long)(row0 + r) * CoutReal + col] = acc[mi][ni][r];
      }
    }
    return;
  }

#pragma unroll
  for (int ni = 0; ni < 2; ++ni) {
    const int col = n0 + wn + ni * 16 + lr;
    const bool ok = col < CoutReal;
    float bs = 0.0f, bsh = 0.0f;
    if (ok) {
      const float inv = rsqrtf(bn_v[col] + 1e-5f);
      bs = bn_g[col] * inv;
      bsh = (cb[col] - bn_m[col]) * bs + bn_b[col];
    }
#pragma unroll
    for (int mi = 0; mi < 4; ++mi) {
      const int row0 = m0 + wm + mi * 16 + (lq << 2);
#pragma unroll
      for (int r = 0; r < 4; ++r) {
        if (ok) {
          const float v = fmaxf(acc[mi][ni][r] * bs + bsh, 0.0f);
          Out[(long long)(row0 + r) * CoutReal + col] = f2b(v);
        }
      }
    }
  }
}

// --------------------------- auxiliary kernels -----------------------------

// patches f32 [64][3][128][128] -> A_pe bf16 [4096 tok][768] (k=c*256+ky*16+kx)
__global__ void pe_gather(const float* __restrict__ patches, u16* __restrict__ Ape) {
  const int t = blockIdx.x, tid = threadIdx.x;
  const int img = t >> 6, pos = t & 63, ty = pos >> 3, tx = pos & 7;
  const float* base = patches + (long long)img * 3 * 128 * 128;
  u16* dst = Ape + (long long)t * 768;
  for (int k = tid; k < 768; k += 256) {
    const int c = k >> 8, rr = k & 255, ky = rr >> 4, kx = rr & 15;
    dst[k] = f2b(base[c * 16384 + (ty * 16 + ky) * 128 + tx * 16 + kx]);
  }
}

// V slice of qkv -> Vt [z=bq*8+h][128 d][512 t] bf16 (LDS transpose)
__global__ void vt_transpose(const u16* __restrict__ qkv, u16* __restrict__ Vt) {
  __shared__ u16 lds[64 * 130];
  const int tt = blockIdx.x;       // t-tile 0..7
  const int z = blockIdx.y;        // 0..63
  const int bq = z >> 3, h = z & 7;
  const int tid = threadIdx.x;
  for (int idx = tid; idx < 64 * 128; idx += 256) {
    const int t = idx >> 7, d = idx & 127;
    lds[t * 130 + d] = qkv[(long long)(bq * 512 + tt * 64 + t) * 3072 + 2048 + h * 128 + d];
  }
  __syncthreads();
  for (int idx = tid; idx < 64 * 128; idx += 256) {
    const int d = idx >> 6, t = idx & 63;
    Vt[(long long)z * 65536 + d * 512 + tt * 64 + t] = lds[t * 130 + d];
  }
}

// in-place row softmax with 1/sqrt(128) scale on bf16 rows of 512
__global__ __launch_bounds__(256) void softmax_rows(u16* __restrict__ P) {
  __shared__ float red[8];
  const long long base = (long long)blockIdx.x * 512;
  const int tid = threadIdx.x;
  const float sc = 0.08838834764831845f;
  float x0 = b2f(P[base + tid]) * sc;
  float x1 = b2f(P[base + tid + 256]) * sc;
  float mx = fmaxf(x0, x1);
  for (int o = 32; o; o >>= 1) mx = fmaxf(mx, __shfl_down(mx, o));
  if ((tid & 63) == 0) red[tid >> 6] = mx;
  __syncthreads();
  mx = fmaxf(fmaxf(red[0], red[1]), fmaxf(red[2], red[3]));
  const float e0 = expf(x0 - mx), e1 = expf(x1 - mx);
  float s = e0 + e1;
  for (int o = 32; o; o >>= 1) s += __shfl_down(s, o);
  __syncthreads();
  if ((tid & 63) == 0) red[tid >> 6] = s;
  __syncthreads();
  s = red[0] + red[1] + red[2] + red[3];
  const float inv = 1.0f / s;
  P[base + tid] = f2b(e0 * inv);
  P[base + tid + 256] = f2b(e1 * inv);
}

// hs_b = LN(hs_b + P; g,b).  P bf16.  One block per row of 1024.
__global__ __launch_bounds__(256) void ln_kernel(
    u16* __restrict__ hsb, const u16* __restrict__ P,
    const float* __restrict__ gw, const float* __restrict__ bw)
{
  __shared__ float red[8];
  const int r = blockIdx.x, tid = threadIdx.x;
  float x[4], s = 0.0f, s2 = 0.0f;
#pragma unroll
  for (int i = 0; i < 4; ++i) {
    const int c = tid + i * 256;
    const float v = b2f(hsb[(long long)r * 1024 + c]) + b2f(P[(long long)r * 1024 + c]);
    x[i] = v; s += v; s2 += v * v;
  }
  for (int o = 32; o; o >>= 1) { s += __shfl_down(s, o); s2 += __shfl_down(s2, o); }
  if ((tid & 63) == 0) { red[tid >> 6] = s; red[4 + (tid >> 6)] = s2; }
  __syncthreads();
  s  = red[0] + red[1] + red[2] + red[3];
  s2 = red[4] + red[5] + red[6] + red[7];
  const float mean = s * (1.0f / 1024.0f);
  const float var = s2 * (1.0f / 1024.0f) - mean * mean;
  const float inv = rsqrtf(var + 1e-5f);
#pragma unroll
  for (int i = 0; i < 4; ++i) {
    const int c = tid + i * 256;
    const float y = (x[i] - mean) * inv * gw[c] + bw[c];
    hsb[(long long)r * 1024 + c] = f2b(y);
  }
}

// repack conv weights f32 [Cout][Cin][3][3] -> bf16 [Npad][9*Cin]
__global__ void repack_w(const float* __restrict__ src, u16* __restrict__ dst, int Cout, int l2c) {
  const int co = blockIdx.x, tid = threadIdx.x;
  const int Cin = 1 << l2c, K9 = 9 << l2c;
  for (int j = tid; j < K9; j += 256) {
    const int t = j >> l2c, ci = j & (Cin - 1);
    u16 v = 0;
    if (co < Cout) v = f2b(src[(long long)(co * Cin + ci) * 9 + t]);
    dst[(long long)co * K9 + j] = v;
  }
}

// bilinear x2 (half-pixel), bf16 NHWC -> bf16 NHWC (2H x 2W)
__global__ void ups2x(const u16* __restrict__ in, u16* __restrict__ out,
                      int l2h, int l2w, int l2c, long long total)
{
  const long long idx = (long long)blockIdx.x * 256 + threadIdx.x;
  if (idx >= total) return;
  const int H = 1 << l2h, W = 1 << l2w, C = 1 << l2c;
  const int c = (int)(idx & (C - 1));
  long long t = idx >> l2c;
  const int ox = (int)(t & (2 * W - 1)); t >>= (l2w + 1);
  const int oy = (int)(t & (2 * H - 1)); t >>= (l2h + 1);
  const int img = (int)t;
  const int iy = oy >> 1, ix = ox >> 1;
  int y0, y1, x0, x1; float wy0, wy1, wx0, wx1;
  if (oy & 1) { y0 = iy; y1 = min(iy + 1, H - 1); wy0 = 0.75f; wy1 = 0.25f; }
  else        { y0 = max(iy - 1, 0); y1 = iy;     wy0 = 0.25f; wy1 = 0.75f; }
  if (ox & 1) { x0 = ix; x1 = min(ix + 1, W - 1); wx0 = 0.75f; wx1 = 0.25f; }
  else        { x0 = max(ix - 1, 0); x1 = ix;     wx0 = 0.25f; wx1 = 0.75f; }
  const u16* base = in + (((long long)img) << (l2h + l2w + l2c));
  const float v00 = b2f(base[((((long long)y0 << l2w) + x0) << l2c) + c]);
  const float v01 = b2f(base[((((long long)y0 << l2w) + x1) << l2c) + c]);
  const float v10 = b2f(base[((((long long)y1 << l2w) + x0) << l2c) + c]);
  const float v11 = b2f(base[((((long long)y1 << l2w) + x1) << l2c) + c]);
  out[idx] = f2b(wy0 * (wx0 * v00 + wx1 * v01) + wy1 * (wx0 * v10 + wx1 * v11));
}

// 1x1 conv over 64 channels: C4 bf16 [262144][64] -> Z f32 [262144]
__global__ __launch_bounds__(256) void conv1x1_final(
    const u16* __restrict__ C4, const float* __restrict__ w5,
    const float* __restrict__ b5, float* __restrict__ Z)
{
  const int tid = threadIdx.x;
  const int px = blockIdx.x * 4 + (tid >> 6);
  const int lane = tid & 63;
  float v = b2f(C4[(long long)px * 64 + lane]) * w5[lane];
  for (int o = 32; o; o >>= 1) v += __shfl_down(v, o);
  if (lane == 0) Z[px] = v + b5[0];
}

// bilinear x2: Z f32 [64][64][64] -> out FLOAT32 [64][128][128]
__global__ void ups_final(const float* __restrict__ Z, float* __restrict__ out) {
  const int idx = blockIdx.x * 256 + threadIdx.x;
  const int ox = idx & 127, oy = (idx >> 7) & 127, img = idx >> 14;
  const int iy = oy >> 1, ix = ox >> 1;
  int y0, y1, x0, x1; float wy0, wy1, wx0, wx1;
  if (oy & 1) { y0 = iy; y1 = min(iy + 1, 63); wy0 = 0.75f; wy1 = 0.25f; }
  else        { y0 = max(iy - 1, 0); y1 = iy;  wy0 = 0.25f; wy1 = 0.75f; }
  if (ox & 1) { x0 = ix; x1 = min(ix + 1, 63); wx0 = 0.75f; wx1 = 0.25f; }
  else        { x0 = max(ix - 1, 0); x1 = ix;  wx0 = 0.25f; wx1 = 0.75f; }
  const float* zi = Z + (long long)img * 4096;
  const float v = wy0 * (wx0 * zi[y0 * 64 + x0] + wx1 * zi[y0 * 64 + x1]) +
                  wy1 * (wx0 * zi[y1 * 64 + x0] + wx1 * zi[y1 * 64 + x1]);
  out[idx] = v;
}

// ---------------------------------------------------------------------------
extern "C" void kernel_launch(void* const* d_in, const int* in_sizes, int n_in,
                              void* d_out, int out_size, void* d_ws, size_t ws_size,
                              hipStream_t stream)
{
  (void)in_sizes; (void)n_in; (void)out_size;
  if (ws_size < 110395648u) return;   // diagnostic: zero output => ws too small
  const float* patches = (const float*)d_in[0];
  const float* pe_w = (const float*)d_in[1];
  const float* pe_b = (const float*)d_in[2];
  const float* qkv_w = (const float*)d_in[3];
  const float* qkv_b = (const float*)d_in[4];
  const float* out_w = (const float*)d_in[5];
  const float* out_b = (const float*)d_in[6];
  const float* ln1_g = (const float*)d_in[7];
  const float* ln1_b = (const float*)d_in[8];
  const float* ff1_w = (const float*)d_in[9];
  const float* ff1_b = (const float*)d_in[10];
  const float* ff2_w = (const float*)d_in[11];
  const float* ff2_b = (const float*)d_in[12];
  const float* ln2_g = (const float*)d_in[13];
  const float* ln2_b = (const float*)d_in[14];
  const float* dwv[4] = {(const float*)d_in[15], (const float*)d_in[21], (const float*)d_in[27], (const float*)d_in[33]};
  const float* dbv[4] = {(const float*)d_in[16], (const float*)d_in[22], (const float*)d_in[28], (const float*)d_in[34]};
  const float* gv[4]  = {(const float*)d_in[17], (const float*)d_in[23], (const float*)d_in[29], (const float*)d_in[35]};
  const float* bev[4] = {(const float*)d_in[18], (const float*)d_in[24], (const float*)d_in[30], (const float*)d_in[36]};
  const float* mv[4]  = {(const float*)d_in[19], (const float*)d_in[25], (const float*)d_in[31], (const float*)d_in[37]};
  const float* vv[4]  = {(const float*)d_in[20], (const float*)d_in[26], (const float*)d_in[32], (const float*)d_in[38]};
  const float* dw5 = (const float*)d_in[39];
  const float* db5 = (const float*)d_in[40];
  float* outp = (float*)d_out;     // reference output dtype = float32
  char* ws = (char*)d_ws;

  // ---- workspace layout (peak 110,395,648 B) ------------------------------
  // transformer phase
  u16* HS_B = (u16*)(ws + 0);              // [4096][1024]
  u16* APE  = (u16*)(ws + 8388608);        // [4096][768] (dead before QKV)
  u16* QKV  = (u16*)(ws + 8388608);        // [4096][3072]   ends 33,554,432
  u16* VT   = (u16*)(ws + 33554432);       // [64][128][512] ends 41,943,040
  u16* SF   = (u16*)(ws + 41943040);       // [64][512][512] ends 75,497,472
  u16* FF1G = (u16*)(ws + 41943040);       // [4096][4096] (over dead SF)
  u16* ATT  = (u16*)(ws + 75497472);       // [4096][1024]   ends 83,886,080
  u16* P_B  = (u16*)(ws + 83886080);       // [4096][1024]   ends 92,274,688
  u16* W1   = (u16*)(ws + 92274688);       // 8.39M slot     ends 100,663,296
  u16* W2   = (u16*)(ws + 100663296);      // 8.39M slot     ends 109,051,904
  float* PART_G  = (float*)(ws + 8388608);  // [2][4096][1024] f32 over dead QKV/VT (proj & FF2, post-PV)
  float* PART_PE = (float*)(ws + 41943040); // [2][4096][1024] f32 over SF region (patch-embed phase only)
  // decoder phase (R3-VERIFIED layout; all transformer buffers except HS_B dead)
  u16* WR1 = (u16*)(ws + 8388608);         // [512][9216]    ends 17,825,792
  u16* WR2 = (u16*)(ws + 17825792);        // [256][4608]    ends 20,185,088
  u16* WR3 = (u16*)(ws + 20185088);        // [128][2304]    ends 20,774,912
  u16* C1  = (u16*)(ws + 20774912);        // [4096][512]    ends 24,969,216
  u16* U1  = (u16*)(ws + 24969216);        // [64][16][16][512] ends 41,746,432
  u16* C2  = (u16*)(ws + 41746432);        // [16384][256]   ends 50,135,040
  u16* U2  = (u16*)(ws + 50135040);        // [64][32][32][256] ends 83,689,472
  u16* C3  = (u16*)(ws + 83689472);        // [65536][128]   ends 100,466,688
  u16* U3  = (u16*)(ws + 8388608);         // [64][64][64][128] = 64MB, ends 75,497,472 (over dead WR1-3/C1/U1/C2 + lower U2)
  u16* C4  = (u16*)(ws + 75497472);        // [262144][64]   ends 109,051,904 (over dead upper-U2/C3/W-slots)
  float* PARTC1 = (float*)(ws + 41746432); // conv1 partials [4][4096][512] f32, ends 75,300,864 (C2/U2 region, unwritten at conv1 time)
  float* PARTC2 = (float*)(ws + 50331648); // conv2 partials [2][16384][256] f32, ends 83,886,080 (disjoint from U1 input & C2 output; C3 written later)
  u16* ZPG = (u16*)(ws + 109051904);       // 256 B zero page (live through all convs)
  u16* WR4 = (u16*)(ws + 109052160);       // [128][1152]    ends 109,347,072
  float* Z = (float*)(ws + 109347072);     // [262144] f32   ends 110,395,648

  // ---- patch embedding (split-K S=2) --------------------------------------
  pe_gather<<<4096, 256, 0, stream>>>(patches, APE);
  cvt_f2b<<<768, 256, 0, stream>>>(pe_w, W1, 786432);
  gemm_bt<<<dim3(8, 32, 2), 256, 0, stream>>>(
      APE, 768, 0, 0, W1, 768, 0, 0,
      HS_B, 1024, 4194304, 0, nullptr, 0, 1, 12, PART_PE);
  reduce_bias<<<4096, 256, 0, stream>>>(PART_PE, 4194304, 2, pe_b, 1024, HS_B, 4194304LL);

  // ---- transformer --------------------------------------------------------
  for (int l = 0; l < 2; ++l) {
    cvt_f2b<<<3072, 256, 0, stream>>>(qkv_w + (long long)l * 3145728, W1, 3145728);
    gemm_bt<<<dim3(24, 32, 1), 256, 0, stream>>>(
        HS_B, 1024, 0, 0, W1, 1024, 0, 0,
        QKV, 3072, 0, 0, qkv_b + l * 3072, 0, 1, 32, nullptr);
    vt_transpose<<<dim3(8, 64), 256, 0, stream>>>(QKV, VT);
    // S = Q K^T for all 64 (batch,head)
    gemm_bt<<<dim3(4, 4, 64), 256, 0, stream>>>(
        QKV, 3072, 1572864, 128, QKV + 1024, 3072, 1572864, 128,
        SF, 512, 2097152, 262144, nullptr, 0, 8, 4, nullptr);
    softmax_rows<<<32768, 256, 0, stream>>>(SF);
    // O = P V
    gemm_bt<<<dim3(1, 4, 64), 256, 0, stream>>>(
        SF, 512, 2097152, 262144, VT, 512, 524288, 65536,
        ATT, 1024, 524288, 128, nullptr, 0, 8, 16, nullptr);
    // proj (split-K S=2; QKV/VT dead now -> PART_G safe)
    cvt_f2b<<<1024, 256, 0, stream>>>(out_w + (long long)l * 1048576, W2, 1048576);
    gemm_bt<<<dim3(8, 32, 2), 256, 0, stream>>>(
        ATT, 1024, 0, 0, W2, 1024, 0, 0,
        P_B, 1024, 4194304, 0, nullptr, 0, 1, 16, PART_G);
    reduce_bias<<<4096, 256, 0, stream>>>(PART_G, 4194304, 2, out_b + l * 1024, 1024, P_B, 4194304LL);
    ln_kernel<<<4096, 256, 0, stream>>>(HS_B, P_B, ln1_g + l * 1024, ln1_b + l * 1024);
    cvt_f2b<<<4096, 256, 0, stream>>>(ff1_w + (long long)l * 4194304, W1, 4194304);
    cvt_f2b<<<4096, 256, 0, stream>>>(ff2_w + (long long)l * 4194304, W2, 4194304);
    gemm_bt<<<dim3(32, 32, 1), 256, 0, stream>>>(
        HS_B, 1024, 0, 0, W1, 1024, 0, 0,
        FF1G, 4096, 0, 0, ff1_b + l * 4096, 1, 1, 32, nullptr);
    // FF2 (split-K S=2, nk=64)
    gemm_bt<<<dim3(8, 32, 2), 256, 0, stream>>>(
        FF1G, 4096, 0, 0, W2, 4096, 0, 0,
        P_B, 1024, 4194304, 0, nullptr, 0, 1, 64, PART_G);
    reduce_bias<<<4096, 256, 0, stream>>>(PART_G, 4194304, 2, ff2_b + l * 1024, 1024, P_B, 4194304LL);
    ln_kernel<<<4096, 256, 0, stream>>>(HS_B, P_B, ln2_g + l * 1024, ln2_b + l * 1024);
  }

  // ---- CNN decoder --------------------------------------------------------
  hipMemsetAsync((void*)ZPG, 0, 256, stream);
  repack_w<<<512, 256, 0, stream>>>(dwv[0], WR1, 512, 10);
  repack_w<<<256, 256, 0, stream>>>(dwv[1], WR2, 256, 9);
  repack_w<<<128, 256, 0, stream>>>(dwv[2], WR3, 128, 8);
  repack_w<<<128, 256, 0, stream>>>(dwv[3], WR4, 64, 7);

  // conv1: split-K S=4 (1024 blocks, 4/CU), partial [4][4096][512] f32
  conv_gemm<<<dim3(32, 8, 4), 256, 0, stream>>>(
      HS_B, WR1, C1, gv[0], bev[0], mv[0], vv[0], dbv[0], ZPG,
      8, 8, 3, 6, 10, 512, 9216, 72, PARTC1, 2097152);
  reduce_bn<<<2048, 256, 0, stream>>>(PARTC1, 2097152, 4,
      gv[0], bev[0], mv[0], vv[0], dbv[0], 512, C1, 2097152LL);
  ups2x<<<32768, 256, 0, stream>>>(C1, U1, 3, 3, 9, 8388608LL);
  // conv2: split-K S=2 (1024 blocks), partial [2][16384][256] f32
  conv_gemm<<<dim3(128, 4, 2), 256, 0, stream>>>(
      U1, WR2, C2, gv[1], bev[1], mv[1], vv[1], dbv[1], ZPG,
      16, 16, 4, 8, 9, 256, 4608, 72, PARTC2, 4194304);
  reduce_bn<<<4096, 256, 0, stream>>>(PARTC2, 4194304, 2,
      gv[1], bev[1], mv[1], vv[1], dbv[1], 256, C2, 4194304LL);
  ups2x<<<65536, 256, 0, stream>>>(C2, U2, 4, 4, 8, 16777216LL);
  conv_gemm<<<dim3(512, 2, 1), 256, 0, stream>>>(
      U2, WR3, C3, gv[2], bev[2], mv[2], vv[2], dbv[2], ZPG,
      32, 32, 5, 10, 8, 128, 2304, 72, nullptr, 0);
  ups2x<<<131072, 256, 0, stream>>>(C3, U3, 5, 5, 7, 33554432LL);
  conv_gemm<<<dim3(2048, 1, 1), 256, 0, stream>>>(
      U3, WR4, C4, gv[3], bev[3], mv[3], vv[3], dbv[3], ZPG,
      64, 64, 6, 12, 7, 64, 1152, 36, nullptr, 0);
  conv1x1_final<<<65536, 256, 0, stream>>>(C4, dw5, db5, Z);
  ups_final<<<4096, 256, 0, stream>>>(Z, outp);
}